// Round 11
// baseline (313.405 us; speedup 1.0000x reference)
//
#include <hip/hip_runtime.h>
#include <hip/hip_bf16.h>

#define BB 32
#define TT 512
#define NV 17
#define C1 64
#define C2 128
#define C3 256
#define NCLS 60

typedef __attribute__((ext_vector_type(8))) short bf16x8;
typedef __attribute__((ext_vector_type(4))) float f32x4;
typedef __attribute__((ext_vector_type(2))) float f32x2;
#define MFMA16(a, b, c) __builtin_amdgcn_mfma_f32_16x16x32_bf16((a), (b), (c), 0, 0, 0)

__device__ __forceinline__ float bf2f(unsigned int u16) {
  union { unsigned int i; float f; } c; c.i = (u16 & 0xffffu) << 16; return c.f;
}
__device__ __forceinline__ unsigned int f2bf(float f) {
  union { float f; unsigned int i; } c; c.f = f;
  unsigned int u = c.i;
  u = (u + 0x7fffu + ((u >> 16) & 1u)) >> 16;
  return u & 0xffffu;
}
__device__ __forceinline__ bf16x8 afrag(const short* buf, int byteoff) {
  return *reinterpret_cast<const bf16x8*>(reinterpret_cast<const char*>(buf) + byteoff);
}

// ---------------- tier-3 (R4) ws layout ----------------
enum : int {
  T3_N    = 0,
  T3_SC1  = 384,
  T3_SH1  = 1472,
  T3_SC2  = 2560,
  T3_SH2  = 4736,
  T3_SC3  = 6912,
  T3_SH3  = 11264,
  T3_W2P  = 15616,
  T3_W3P  = 19712,
  T3_PS1  = 36096,
  T3_PQ1  = 593152,
  T3_PS2  = 1150208,
  T3_PQ2  = 2264320,
  T3_PS3  = 3378432,      // 1024*4352
  T3_PQ3  = 7834880,
  T3_M1   = 12291328,     // 1024*8704
  T3_H1   = 21204224,     // 16384*1088
  T3_END  = 39030016,     // ~156.1 MB
};

// ---------------- tier-4 ws layout: H1 (f32) + H2 (bf16 [tile][p][v][tid]) ----
enum : int {
  T4_N    = 0,
  T4_SC1  = 384,
  T4_SH1  = 1472,
  T4_SC2  = 2560,
  T4_SH2  = 4736,
  T4_SC3  = 6912,
  T4_SH3  = 11264,
  T4_W2P  = 15616,
  T4_W3P  = 19712,
  T4_PS1  = 36096,
  T4_PQ1  = 593152,
  T4_PP   = 1150208,      // head1 partials: 256 blocks * 256 floats
  T4_PQ2  = 2264320,
  T4_PS3  = 3378432,      // 1024*4352 (also pass2g partial scratch)
  T4_PQ3  = 7834880,
  T4_H1   = 12291328,     // 16384*1088 f32
  T4_H2   = 30117120,     // 1024 tiles * 2p * 17v * 512 uint (71.3MB)
  T4_END  = 47942912,     // ~191.8 MB
};

__global__ __launch_bounds__(64) void build_Npad(const int* __restrict__ ei, float* __restrict__ Nout) {
  __shared__ float A[NV][NV];
  __shared__ float dinv[NV];
  int tid = threadIdx.x;
  for (int i = tid; i < NV * NV; i += 64) A[i / NV][i % NV] = 0.f;
  __syncthreads();
  if (tid == 0) {
    for (int e = 0; e < 36; e++) {
      int s = ei[e], d = ei[36 + e];
      A[d][s] += 1.f;
    }
    for (int v = 0; v < NV; v++) A[v][v] += 1.f;
  }
  __syncthreads();
  if (tid < NV) {
    float s = 0.f;
    for (int u = 0; u < NV; u++) s += A[tid][u];
    dinv[tid] = rsqrtf(s);
  }
  __syncthreads();
  for (int i = tid; i < 340; i += 64) {
    int v = i / 20, u = i % 20;
    Nout[i] = (u < NV) ? dinv[v] * A[v][u] * dinv[u] : 0.f;
  }
}

// repack W2 [64][128] and W3 [128][256] fp32 into bf16 MFMA B-fragments.
__global__ __launch_bounds__(256) void repackk(const float* __restrict__ W2, const float* __restrict__ W3,
                                               short* __restrict__ W2p, short* __restrict__ W3p) {
  int id = blockIdx.x * 256 + threadIdx.x;
  if (id < 8192) {
    int e = id & 7, lane = (id >> 3) & 63, fid = id >> 9;
    int nt = fid >> 1, ks = fid & 1;
    int k = ks * 32 + (lane >> 4) * 8 + e, n = nt * 16 + (lane & 15);
    W2p[id] = (short)f2bf(W2[k * 128 + n]);
  } else if (id < 40960) {
    int j = id - 8192;
    int e = j & 7, lane = (j >> 3) & 63, fid = j >> 9;
    int nt = fid >> 2, ks = fid & 3;
    int k = ks * 32 + (lane >> 4) * 8 + e, n = nt * 16 + (lane & 15);
    W3p[j] = (short)f2bf(W3[k * 256 + n]);
  }
}

// pass1w (tier-4, R10): mix1 -> H1 via NON-TEMPORAL stores. R9 counters showed
// FETCH 95MB on a kernel that reads 3.3MB: read-for-ownership on the streamed
// H1 stores. nt stores bypass the RFO.
__global__ __launch_bounds__(512) void pass1w(const float* __restrict__ x, const float* __restrict__ Nw,
                                              const float* __restrict__ W1, const float* __restrict__ b1,
                                              float* __restrict__ H1o) {
  __shared__ float xr[32][52];
  __shared__ float Ns[340];
  __shared__ float W1s[192];
  __shared__ float b1s[64];
  int tid = threadIdx.x;
  for (int i = tid; i < 340; i += 512) Ns[i] = Nw[i];
  for (int i = tid; i < 192; i += 512) W1s[i] = W1[i];
  if (tid < 64) b1s[tid] = b1[tid];
  int rbase = blockIdx.x * 32;
  for (int i = tid; i < 32 * 51; i += 512) xr[i / 51][i % 51] = x[(size_t)(rbase + i / 51) * 51 + i % 51];
  int c2 = tid & 31, rg = tid >> 5;
  int c = c2 * 2;
  __syncthreads();
  float w1a0 = W1s[c], w1a1 = W1s[c + 1];
  float w1b0 = W1s[64 + c], w1b1 = W1s[64 + c + 1];
  float w1c0 = W1s[128 + c], w1c1 = W1s[128 + c + 1];
  float bb0 = b1s[c], bb1 = b1s[c + 1];
#pragma unroll 1
  for (int rr = 0; rr < 2; rr++) {
    int r = rg + rr * 16;
    float y0[17], y1v[17];
#pragma unroll
    for (int u = 0; u < 17; u++) {
      float xa = xr[r][u * 3], xb = xr[r][u * 3 + 1], xc = xr[r][u * 3 + 2];
      y0[u] = xa * w1a0 + xb * w1b0 + xc * w1c0;
      y1v[u] = xa * w1a1 + xb * w1b1 + xc * w1c1;
    }
#pragma unroll
    for (int v = 0; v < 17; v++) {
      float a0 = 0.f, a1 = 0.f;
#pragma unroll
      for (int u0 = 0; u0 < 16; u0 += 4) {
        float4 n4 = *reinterpret_cast<const float4*>(&Ns[v * 20 + u0]);
        a0 += n4.x * y0[u0] + n4.y * y0[u0 + 1] + n4.z * y0[u0 + 2] + n4.w * y0[u0 + 3];
        a1 += n4.x * y1v[u0] + n4.y * y1v[u0 + 1] + n4.z * y1v[u0 + 2] + n4.w * y1v[u0 + 3];
      }
      float n16 = Ns[v * 20 + 16];
      a0 += n16 * y0[16]; a1 += n16 * y1v[16];
      float h0 = fmaxf(a0 + bb0, 0.f), h1 = fmaxf(a1 + bb1, 0.f);
      f32x2 hv; hv.x = h0; hv.y = h1;
      __builtin_nontemporal_store(hv,
          reinterpret_cast<f32x2*>(&H1o[(size_t)(rbase + r) * 1088 + v * 64 + c]));
    }
  }
}

// stats1k (tier-4, R10): NT loads of H1, NT stores of partials.
__global__ __launch_bounds__(512) void stats1k(const float* __restrict__ H1,
                                               float* __restrict__ Ps1, float* __restrict__ Pq1) {
  const int tid = threadIdx.x;
  const size_t rbase = (size_t)blockIdx.x * 32;
  for (int ch = tid; ch < 1088; ch += 512) {
    float s = 0.f, q = 0.f;
#pragma unroll 4
    for (int r = 0; r < 32; r++) {
      float v = __builtin_nontemporal_load(&H1[(rbase + r) * 1088 + ch]);
      s += v; q += v * v;
    }
    __builtin_nontemporal_store(s, &Ps1[(size_t)blockIdx.x * 1088 + ch]);
    __builtin_nontemporal_store(q, &Pq1[(size_t)blockIdx.x * 1088 + ch]);
  }
}

// pass1k (tier-3): stats of relu(N(xW1)+b1); saves h1.
__global__ __launch_bounds__(512) void pass1k(const float* __restrict__ x, const float* __restrict__ Nw,
                                              const float* __restrict__ W1, const float* __restrict__ b1,
                                              float* __restrict__ Ps1, float* __restrict__ Pq1,
                                              float* __restrict__ H1o) {
  __shared__ float scratch[16 * 17 * 64];
  __shared__ float xr[32][52];
  __shared__ float Ns[340];
  __shared__ float W1s[192];
  __shared__ float b1s[64];
  int tid = threadIdx.x;
  const bool saveH = (H1o != nullptr);
  for (int i = tid; i < 340; i += 512) Ns[i] = Nw[i];
  for (int i = tid; i < 192; i += 512) W1s[i] = W1[i];
  if (tid < 64) b1s[tid] = b1[tid];
  int rbase = blockIdx.x * 32;
  for (int i = tid; i < 32 * 51; i += 512) xr[i / 51][i % 51] = x[(size_t)(rbase + i / 51) * 51 + i % 51];
  int c2 = tid & 31, rg = tid >> 5;
  int c = c2 * 2;
  float s0[17], s1[17], q0[17], q1[17];
#pragma unroll
  for (int v = 0; v < 17; v++) { s0[v] = 0.f; s1[v] = 0.f; q0[v] = 0.f; q1[v] = 0.f; }
  __syncthreads();
  float w1a0 = W1s[c], w1a1 = W1s[c + 1];
  float w1b0 = W1s[64 + c], w1b1 = W1s[64 + c + 1];
  float w1c0 = W1s[128 + c], w1c1 = W1s[128 + c + 1];
  float bb0 = b1s[c], bb1 = b1s[c + 1];
  for (int rr = 0; rr < 2; rr++) {
    int r = rg + rr * 16;
    float y0[17], y1v[17];
#pragma unroll
    for (int u = 0; u < 17; u++) {
      float xa = xr[r][u * 3], xb = xr[r][u * 3 + 1], xc = xr[r][u * 3 + 2];
      y0[u] = xa * w1a0 + xb * w1b0 + xc * w1c0;
      y1v[u] = xa * w1a1 + xb * w1b1 + xc * w1c1;
    }
#pragma unroll
    for (int v = 0; v < 17; v++) {
      float a0 = 0.f, a1 = 0.f;
#pragma unroll
      for (int u0 = 0; u0 < 16; u0 += 4) {
        float4 n4 = *reinterpret_cast<const float4*>(&Ns[v * 20 + u0]);
        a0 += n4.x * y0[u0] + n4.y * y0[u0 + 1] + n4.z * y0[u0 + 2] + n4.w * y0[u0 + 3];
        a1 += n4.x * y1v[u0] + n4.y * y1v[u0 + 1] + n4.z * y1v[u0 + 2] + n4.w * y1v[u0 + 3];
      }
      float n16 = Ns[v * 20 + 16];
      a0 += n16 * y0[16]; a1 += n16 * y1v[16];
      float h0 = fmaxf(a0 + bb0, 0.f), h1 = fmaxf(a1 + bb1, 0.f);
      if (saveH)
        *reinterpret_cast<float2*>(&H1o[(size_t)(rbase + r) * 1088 + v * 64 + c]) = make_float2(h0, h1);
      s0[v] += h0; q0[v] += h0 * h0;
      s1[v] += h1; q1[v] += h1 * h1;
    }
  }
#pragma unroll
  for (int v = 0; v < 17; v++)
    *reinterpret_cast<float2*>(&scratch[(rg * 17 + v) * 64 + c]) = make_float2(s0[v], s1[v]);
  __syncthreads();
  for (int i = tid; i < 1088; i += 512) {
    float a = 0.f;
#pragma unroll
    for (int r2 = 0; r2 < 16; r2++) a += scratch[(r2 * 17 + (i >> 6)) * 64 + (i & 63)];
    Ps1[(size_t)blockIdx.x * 1088 + i] = a;
  }
  __syncthreads();
#pragma unroll
  for (int v = 0; v < 17; v++)
    *reinterpret_cast<float2*>(&scratch[(rg * 17 + v) * 64 + c]) = make_float2(q0[v], q1[v]);
  __syncthreads();
  for (int i = tid; i < 1088; i += 512) {
    float a = 0.f;
#pragma unroll
    for (int r2 = 0; r2 < 16; r2++) a += scratch[(r2 * 17 + (i >> 6)) * 64 + (i & 63)];
    Pq1[(size_t)blockIdx.x * 1088 + i] = a;
  }
}

// finalize BN: sum partials -> scale/shift. Variable block size.
__global__ __launch_bounds__(1024) void finalize_k(const float* __restrict__ Ps, const float* __restrict__ Pq,
                                                   int P, int C, const float* __restrict__ g,
                                                   const float* __restrict__ be, float* __restrict__ sc,
                                                   float* __restrict__ sh) {
  __shared__ float rs[16][64], rq[16][64];
  int l = threadIdx.x & 63, w = threadIdx.x >> 6;
  int ng = blockDim.x >> 6;
  int i = blockIdx.x * 64 + l;
  float s = 0.f, q = 0.f;
  if (i < C) {
    for (int p = w; p < P; p += ng) { s += Ps[(size_t)p * C + i]; q += Pq[(size_t)p * C + i]; }
  }
  rs[w][l] = s; rq[w][l] = q;
  __syncthreads();
  if (w == 0 && i < C) {
    s = 0.f; q = 0.f;
    for (int t = 0; t < ng; t++) { s += rs[t][l]; q += rq[t][l]; }
    float m = s * (1.f / 16384.f);
    float var = q * (1.f / 16384.f) - m * m;
    float r = rsqrtf(var + 1e-5f);
    sc[i] = g[i] * r;
    sh[i] = be[i] - m * g[i] * r;
  }
}

// pass2g (tier-4, R10): NT loads of H1; NT stores of H2 (as packed uint) and
// stat partials.
__global__ __launch_bounds__(512) void pass2g(const float* __restrict__ H1, const float* __restrict__ Nw,
                                              const float* __restrict__ sc1, const float* __restrict__ sh1,
                                              const short* __restrict__ W2p, const float* __restrict__ b2,
                                              float* __restrict__ Ps2, float* __restrict__ Pq2,
                                              unsigned int* __restrict__ H2) {
  __shared__ __align__(16) short m1A[17408];
  __shared__ float stats[4352];
  __shared__ float Ns[340];
  __shared__ float b2s[128];
  __shared__ float sc1s[1088], sh1s[1088];
  const int tid = threadIdx.x;
  const int lane = tid & 63, w = tid >> 6;
  const int row = lane & 15, g = lane >> 4;
  for (int i = tid; i < 340; i += 512) Ns[i] = Nw[i];
  if (tid < 128) b2s[tid] = b2[tid];
  for (int i = tid; i < 1088; i += 512) { sc1s[i] = sc1[i]; sh1s[i] = sh1[i]; }
  bf16x8 w2f0 = *reinterpret_cast<const bf16x8*>(&W2p[((w * 2 + 0) * 64 + lane) * 8]);
  bf16x8 w2f1 = *reinterpret_cast<const bf16x8*>(&W2p[((w * 2 + 1) * 64 + lane) * 8]);
  const int r_mix = tid >> 5;
  const int c2 = tid & 31;
  const int c = c2 * 2;
  const int tile = blockIdx.x;
  const int rbase = blockIdx.x * 16;
  __syncthreads();
  {
    const float* hrow = H1 + (size_t)(rbase + r_mix) * 1088;
    float t0[17], t1[17];
#pragma unroll
    for (int v = 0; v < 17; v++) {
      f32x2 hv = __builtin_nontemporal_load(reinterpret_cast<const f32x2*>(&hrow[v * 64 + c]));
      float2 scv = *reinterpret_cast<const float2*>(&sc1s[v * 64 + c]);
      float2 shv = *reinterpret_cast<const float2*>(&sh1s[v * 64 + c]);
      t0[v] = hv.x * scv.x + shv.x;
      t1[v] = hv.y * scv.y + shv.y;
    }
#pragma unroll
    for (int v = 0; v < 17; v++) {
      float a0 = 0.f, a1 = 0.f;
#pragma unroll
      for (int u0 = 0; u0 < 16; u0 += 4) {
        float4 n4 = *reinterpret_cast<const float4*>(&Ns[v * 20 + u0]);
        a0 += n4.x * t0[u0] + n4.y * t0[u0 + 1] + n4.z * t0[u0 + 2] + n4.w * t0[u0 + 3];
        a1 += n4.x * t1[u0] + n4.y * t1[u0 + 1] + n4.z * t1[u0 + 2] + n4.w * t1[u0 + 3];
      }
      float n16 = Ns[v * 20 + 16];
      a0 += n16 * t0[16]; a1 += n16 * t1[16];
      unsigned int pk = (f2bf(a1) << 16) | f2bf(a0);
      int off = v * 2048 + r_mix * 128 + ((c2 * 4) ^ ((r_mix & 7) << 4));
      *reinterpret_cast<unsigned int*>(reinterpret_cast<char*>(m1A) + off) = pk;
    }
  }
  __syncthreads();
#pragma unroll 1
  for (int v = 0; v < 17; v++) {
    int ab = v * 2048 + row * 128;
    int sw = (row & 7) << 4;
    bf16x8 a0 = afrag(m1A, ab + ((g * 16) ^ sw));
    bf16x8 a1 = afrag(m1A, ab + ((64 + g * 16) ^ sw));
    f32x4 acc = {0.f, 0.f, 0.f, 0.f};
    acc = MFMA16(a0, w2f0, acc);
    acc = MFMA16(a1, w2f1, acc);
    int cc = w * 16 + row;
    float bb = b2s[cc];
    float hj0 = fmaxf(acc[0] + bb, 0.f);
    float hj1 = fmaxf(acc[1] + bb, 0.f);
    float hj2 = fmaxf(acc[2] + bb, 0.f);
    float hj3 = fmaxf(acc[3] + bb, 0.f);
    unsigned int e0 = (f2bf(hj1) << 16) | f2bf(hj0);
    unsigned int e1 = (f2bf(hj3) << 16) | f2bf(hj2);
    __builtin_nontemporal_store(e0, &H2[(((size_t)tile * 2 + 0) * 17 + v) * 512 + tid]);
    __builtin_nontemporal_store(e1, &H2[(((size_t)tile * 2 + 1) * 17 + v) * 512 + tid]);
    float s = hj0 + hj1 + hj2 + hj3;
    float q = hj0 * hj0 + hj1 * hj1 + hj2 * hj2 + hj3 * hj3;
    s += __shfl_xor(s, 16); s += __shfl_xor(s, 32);
    q += __shfl_xor(q, 16); q += __shfl_xor(q, 32);
    if (g == 0) {
      stats[v * 128 + cc] = s;
      stats[2176 + v * 128 + cc] = q;
    }
  }
  __syncthreads();
  for (int i = tid; i < 2176; i += 512) {
    __builtin_nontemporal_store(stats[i], &Ps2[(size_t)blockIdx.x * 2176 + i]);
    __builtin_nontemporal_store(stats[2176 + i], &Pq2[(size_t)blockIdx.x * 2176 + i]);
  }
}

// pass3h (tier-4, R10): accumulate-into-outputs mix3; NT loads of H2 (uint),
// NT stores of Ps3/Pq3.
__global__ __launch_bounds__(512) void pass3h(const unsigned int* __restrict__ H2, const float* __restrict__ Nw,
                                              const float* __restrict__ sc2, const float* __restrict__ sh2,
                                              const short* __restrict__ W3p, const float* __restrict__ b3,
                                              float* __restrict__ Ps3, float* __restrict__ Pq3) {
  __shared__ __align__(16) short M2S[34816];    // m2A [17][16][128] bf16, swizzled
  __shared__ float Ns[340];
  __shared__ float b3s[256];
  const int tid = threadIdx.x;
  const int lane = tid & 63, w = tid >> 6;
  const int row = lane & 15, g = lane >> 4;
  const int cc = w * 16 + row;
  const int tile = blockIdx.x;
  for (int i = tid; i < 340; i += 512) Ns[i] = Nw[i];
  if (tid < 256) b3s[tid] = b3[tid];
  __syncthreads();
  const int sw = (row & 7) << 4;
#pragma unroll 1
  for (int p = 0; p < 2; p++) {
    float o0[17], o1[17];
#pragma unroll
    for (int vp = 0; vp < 17; vp++) { o0[vp] = 0.f; o1[vp] = 0.f; }
#pragma unroll 1
    for (int v = 0; v < 17; v++) {
      unsigned int hv = __builtin_nontemporal_load(&H2[(((size_t)tile * 2 + p) * 17 + v) * 512 + tid]);
      float scv = sc2[v * 128 + cc], shv = sh2[v * 128 + cc];
      float t0 = bf2f(hv) * scv + shv;
      float t1 = bf2f(hv >> 16) * scv + shv;
#pragma unroll
      for (int vp = 0; vp < 17; vp++) {
        float n = Ns[vp * 20 + v];
        o0[vp] += n * t0;
        o1[vp] += n * t1;
      }
    }
    const int r0 = 4 * g + 2 * p, r1 = r0 + 1;
    const int sw0 = (r0 & 7) << 4, sw1 = (r1 & 7) << 4;
#pragma unroll
    for (int vp = 0; vp < 17; vp++) {
      *reinterpret_cast<short*>(reinterpret_cast<char*>(M2S) + vp * 4096 + r0 * 256 + ((cc * 2) ^ sw0)) =
          (short)f2bf(o0[vp]);
      *reinterpret_cast<short*>(reinterpret_cast<char*>(M2S) + vp * 4096 + r1 * 256 + ((cc * 2) ^ sw1)) =
          (short)f2bf(o1[vp]);
    }
  }
  __syncthreads();
  {
    int z3 = 0;
    asm volatile("" : "+v"(z3));
    bf16x8 w3f0[4], w3f1[4];
#pragma unroll
    for (int ks = 0; ks < 4; ks++) {
      w3f0[ks] = *reinterpret_cast<const bf16x8*>(&W3p[(((w * 2 + 0) * 4 + ks) * 64 + lane) * 8 + z3]);
      w3f1[ks] = *reinterpret_cast<const bf16x8*>(&W3p[(((w * 2 + 1) * 4 + ks) * 64 + lane) * 8 + z3]);
    }
#pragma unroll 1
    for (int v = 0; v < 17; v++) {
      int ab = v * 4096 + row * 256;
      bf16x8 a[4];
#pragma unroll
      for (int ks = 0; ks < 4; ks++) a[ks] = afrag(M2S, ab + ((ks * 64 + g * 16) ^ sw));
      f32x4 acc0 = {0.f, 0.f, 0.f, 0.f}, acc1 = {0.f, 0.f, 0.f, 0.f};
#pragma unroll
      for (int ks = 0; ks < 4; ks++) {
        acc0 = MFMA16(a[ks], w3f0[ks], acc0);
        acc1 = MFMA16(a[ks], w3f1[ks], acc1);
      }
      int cA = w * 32 + row, cB = w * 32 + 16 + row;
      float bbA = b3s[cA], bbB = b3s[cB];
      float s0 = 0.f, q0 = 0.f, s1 = 0.f, q1 = 0.f;
#pragma unroll
      for (int j = 0; j < 4; j++) {
        float hA = fmaxf(acc0[j] + bbA, 0.f);
        float hB = fmaxf(acc1[j] + bbB, 0.f);
        s0 += hA; q0 += hA * hA;
        s1 += hB; q1 += hB * hB;
      }
      s0 += __shfl_xor(s0, 16); s0 += __shfl_xor(s0, 32);
      q0 += __shfl_xor(q0, 16); q0 += __shfl_xor(q0, 32);
      s1 += __shfl_xor(s1, 16); s1 += __shfl_xor(s1, 32);
      q1 += __shfl_xor(q1, 16); q1 += __shfl_xor(q1, 32);
      if (g == 0) {
        size_t o = (size_t)tile * 4352 + v * 256;
        __builtin_nontemporal_store(s0, &Ps3[o + cA]);
        __builtin_nontemporal_store(q0, &Pq3[o + cA]);
        __builtin_nontemporal_store(s1, &Ps3[o + cB]);
        __builtin_nontemporal_store(q1, &Pq3[o + cB]);
      }
    }
  }
}

// head1: grid 32b x 8part, 256 thr. Partial sc3-weighted slice sums (NT loads).
__global__ __launch_bounds__(256) void head1(const float* __restrict__ Ps3, const float* __restrict__ sc3,
                                             float* __restrict__ pp) {
  const int b = blockIdx.x >> 3, part = blockIdx.x & 7;
  const int tid = threadIdx.x;
  float a = 0.f;
#pragma unroll
  for (int v = 0; v < 17; v++) {
    float sbv = 0.f;
#pragma unroll
    for (int s2 = 0; s2 < 4; s2++)
      sbv += __builtin_nontemporal_load(&Ps3[(size_t)(b * 32 + part * 4 + s2) * 4352 + v * 256 + tid]);
    a += sc3[v * 256 + tid] * sbv;
  }
  pp[(size_t)blockIdx.x * 256 + tid] = a;
}

// head2: grid 32, 256 thr. Sum partials + sh3 term, then 256x60 GEMM.
__global__ __launch_bounds__(256) void head2(const float* __restrict__ pp, const float* __restrict__ sh3,
                                             const float* __restrict__ Wf, const float* __restrict__ bf_,
                                             float* __restrict__ out) {
  __shared__ float pl[C3];
  const int b = blockIdx.x, tid = threadIdx.x;
  float a = 0.f;
#pragma unroll
  for (int p = 0; p < 8; p++) a += pp[(size_t)(b * 8 + p) * 256 + tid];
  float shs = 0.f;
#pragma unroll
  for (int v = 0; v < 17; v++) shs += sh3[v * 256 + tid];
  pl[tid] = a * (1.f / 8704.f) + shs * (1.f / 17.f);
  __syncthreads();
  if (tid < NCLS) {
    float acc = bf_[tid];
#pragma unroll 4
    for (int cc = 0; cc < C3; cc++) acc += pl[cc] * Wf[cc * NCLS + tid];
    out[b * NCLS + tid] = acc;
  }
}

// pass2h (tier-3): streams h1, saves m1A tiles to M1.
__global__ __launch_bounds__(512) void pass2h(const float* __restrict__ H1, const float* __restrict__ Nw,
                                              const float* __restrict__ sc1, const float* __restrict__ sh1,
                                              const short* __restrict__ W2p, const float* __restrict__ b2,
                                              float* __restrict__ Ps2, float* __restrict__ Pq2,
                                              float* __restrict__ M1) {
  __shared__ __align__(16) short m1A[17408];
  __shared__ float stats[4352];
  __shared__ float Ns[340];
  __shared__ float b2s[128];
  __shared__ float sc1s[1088], sh1s[1088];
  const int tid = threadIdx.x;
  const int lane = tid & 63, w = tid >> 6;
  const int row = lane & 15, g = lane >> 4;
  for (int i = tid; i < 340; i += 512) Ns[i] = Nw[i];
  if (tid < 128) b2s[tid] = b2[tid];
  for (int i = tid; i < 1088; i += 512) { sc1s[i] = sc1[i]; sh1s[i] = sh1[i]; }
  for (int i = tid; i < 4352; i += 512) stats[i] = 0.f;
  bf16x8 w2f0 = *reinterpret_cast<const bf16x8*>(&W2p[((w * 2 + 0) * 64 + lane) * 8]);
  bf16x8 w2f1 = *reinterpret_cast<const bf16x8*>(&W2p[((w * 2 + 1) * 64 + lane) * 8]);
  const int r_mix = tid >> 5;
  const int c2 = tid & 31;
  const int c = c2 * 2;
  __syncthreads();
  for (int chunk = 0; chunk < 2; chunk++) {
    const int rbase = blockIdx.x * 32 + chunk * 16;
    {
      const float* hrow = H1 + (size_t)(rbase + r_mix) * 1088;
      float t0[17], t1[17];
#pragma unroll
      for (int v = 0; v < 17; v++) {
        float2 hv = *reinterpret_cast<const float2*>(&hrow[v * 64 + c]);
        float2 scv = *reinterpret_cast<const float2*>(&sc1s[v * 64 + c]);
        float2 shv = *reinterpret_cast<const float2*>(&sh1s[v * 64 + c]);
        t0[v] = hv.x * scv.x + shv.x;
        t1[v] = hv.y * scv.y + shv.y;
      }
#pragma unroll
      for (int v = 0; v < 17; v++) {
        float a0 = 0.f, a1 = 0.f;
#pragma unroll
        for (int u0 = 0; u0 < 16; u0 += 4) {
          float4 n4 = *reinterpret_cast<const float4*>(&Ns[v * 20 + u0]);
          a0 += n4.x * t0[u0] + n4.y * t0[u0 + 1] + n4.z * t0[u0 + 2] + n4.w * t0[u0 + 3];
          a1 += n4.x * t1[u0] + n4.y * t1[u0 + 1] + n4.z * t1[u0 + 2] + n4.w * t1[u0 + 3];
        }
        float n16 = Ns[v * 20 + 16];
        a0 += n16 * t0[16]; a1 += n16 * t1[16];
        unsigned int pk = (f2bf(a1) << 16) | f2bf(a0);
        int off = v * 2048 + r_mix * 128 + ((c2 * 4) ^ ((r_mix & 7) << 4));
        *reinterpret_cast<unsigned int*>(reinterpret_cast<char*>(m1A) + off) = pk;
      }
    }
    __syncthreads();
#pragma unroll 1
    for (int v = 0; v < 17; v++) {
      int ab = v * 2048 + row * 128;
      int sw = (row & 7) << 4;
      bf16x8 a0 = afrag(m1A, ab + ((g * 16) ^ sw));
      bf16x8 a1 = afrag(m1A, ab + ((64 + g * 16) ^ sw));
      f32x4 acc = {0.f, 0.f, 0.f, 0.f};
      acc = MFMA16(a0, w2f0, acc);
      acc = MFMA16(a1, w2f1, acc);
      int cc = w * 16 + row;
      float bb = b2s[cc];
      float s = 0.f, q = 0.f;
#pragma unroll
      for (int j = 0; j < 4; j++) {
        float h = fmaxf(acc[j] + bb, 0.f);
        s += h; q += h * h;
      }
      s += __shfl_xor(s, 16); s += __shfl_xor(s, 32);
      q += __shfl_xor(q, 16); q += __shfl_xor(q, 32);
      if (g == 0) {
        stats[v * 128 + cc] += s;
        stats[2176 + v * 128 + cc] += q;
      }
    }
    {
      const int tile = blockIdx.x * 2 + chunk;
      float4* dst = reinterpret_cast<float4*>(M1 + (size_t)tile * 8704);
      const float4* src = reinterpret_cast<const float4*>(m1A);
      for (int i = tid; i < 2176; i += 512) dst[i] = src[i];
    }
    __syncthreads();
  }
  for (int i = tid; i < 2176; i += 512) {
    Ps2[(size_t)blockIdx.x * 2176 + i] = stats[i];
    Pq2[(size_t)blockIdx.x * 2176 + i] = stats[2176 + i];
  }
}

// pass3r (tier-3): register-resident pipeline over nchunk 16-row tiles.
__global__ __launch_bounds__(512) void pass3r(const float* __restrict__ M1, const float* __restrict__ Nw,
                                              const short* __restrict__ W2p, const float* __restrict__ b2,
                                              const float* __restrict__ sc2, const float* __restrict__ sh2,
                                              const short* __restrict__ W3p, const float* __restrict__ b3,
                                              float* __restrict__ Ps3, float* __restrict__ Pq3,
                                              int nchunk) {
  __shared__ __align__(16) char BUFA[34816];
  __shared__ __align__(16) short M2S[34816];
  __shared__ float Ns[340];
  __shared__ float b2s[128], b3s[256];
  __shared__ float sc2s[2176], sh2s[2176];
  const int tid = threadIdx.x;
  const int lane = tid & 63, w = tid >> 6;
  const int row = lane & 15, g = lane >> 4;
  const int cc = w * 16 + row;
  for (int i = tid; i < 340; i += 512) Ns[i] = Nw[i];
  if (tid < 128) b2s[tid] = b2[tid];
  if (tid < 256) b3s[tid] = b3[tid];
  for (int i = tid; i < 2176; i += 512) { sc2s[i] = sc2[i]; sh2s[i] = sh2[i]; }
  bf16x8 w2f0 = *reinterpret_cast<const bf16x8*>(&W2p[((w * 2 + 0) * 64 + lane) * 8]);
  bf16x8 w2f1 = *reinterpret_cast<const bf16x8*>(&W2p[((w * 2 + 1) * 64 + lane) * 8]);
  short* m1A = reinterpret_cast<short*>(BUFA);
  float* st  = reinterpret_cast<float*>(BUFA);
  __syncthreads();
  const float bb2 = b2s[cc];
  const int sw = (row & 7) << 4;
  for (int chunk = 0; chunk < nchunk; chunk++) {
    {
      const int tile = blockIdx.x * nchunk + chunk;
      const float4* src = reinterpret_cast<const float4*>(M1 + (size_t)tile * 8704);
      float4* dst = reinterpret_cast<float4*>(m1A);
      for (int i = tid; i < 2176; i += 512) dst[i] = src[i];
    }
    __syncthreads();
    float h[17][4];
#pragma unroll
    for (int v = 0; v < 17; v++) {
      int ab = v * 2048 + row * 128;
      bf16x8 a0 = afrag(m1A, ab + ((g * 16) ^ sw));
      bf16x8 a1 = afrag(m1A, ab + ((64 + g * 16) ^ sw));
      f32x4 acc = {0.f, 0.f, 0.f, 0.f};
      acc = MFMA16(a0, w2f0, acc);
      acc = MFMA16(a1, w2f1, acc);
      float scv = sc2s[v * 128 + cc], shv = sh2s[v * 128 + cc];
#pragma unroll
      for (int j = 0; j < 4; j++) h[v][j] = fmaxf(acc[j] + bb2, 0.f) * scv + shv;
      __builtin_amdgcn_sched_barrier(0);
    }
    __syncthreads();
    for (int i = tid; i < 8704; i += 512) st[i] = 0.f;
#pragma unroll
    for (int j = 0; j < 4; j++) {
      const int r = 4 * g + j;
      const int swr = (r & 7) << 4;
#pragma unroll
      for (int v = 0; v < 17; v++) {
        float a = 0.f;
#pragma unroll
        for (int u0 = 0; u0 < 16; u0 += 4) {
          float4 n4 = *reinterpret_cast<const float4*>(&Ns[v * 20 + u0]);
          a += n4.x * h[u0][j] + n4.y * h[u0 + 1][j] + n4.z * h[u0 + 2][j] + n4.w * h[u0 + 3][j];
        }
        a += Ns[v * 20 + 16] * h[16][j];
        int off = v * 4096 + r * 256 + ((cc * 2) ^ swr);
        *reinterpret_cast<short*>(reinterpret_cast<char*>(M2S) + off) = (short)f2bf(a);
      }
    }
    __syncthreads();
    {
      int z3 = 0;
      asm volatile("" : "+v"(z3));
      bf16x8 w3f0[4], w3f1[4];
#pragma unroll
      for (int ks = 0; ks < 4; ks++) {
        w3f0[ks] = *reinterpret_cast<const bf16x8*>(&W3p[(((w * 2 + 0) * 4 + ks) * 64 + lane) * 8 + z3]);
        w3f1[ks] = *reinterpret_cast<const bf16x8*>(&W3p[(((w * 2 + 1) * 4 + ks) * 64 + lane) * 8 + z3]);
      }
#pragma unroll 1
      for (int v = 0; v < 17; v++) {
        int ab = v * 4096 + row * 256;
        bf16x8 a[4];
#pragma unroll
        for (int ks = 0; ks < 4; ks++) a[ks] = afrag(M2S, ab + ((ks * 64 + g * 16) ^ sw));
        f32x4 acc0 = {0.f, 0.f, 0.f, 0.f}, acc1 = {0.f, 0.f, 0.f, 0.f};
#pragma unroll
        for (int ks = 0; ks < 4; ks++) {
          acc0 = MFMA16(a[ks], w3f0[ks], acc0);
          acc1 = MFMA16(a[ks], w3f1[ks], acc1);
        }
        int cA = w * 32 + row, cB = w * 32 + 16 + row;
        float bbA = b3s[cA], bbB = b3s[cB];
        float s0 = 0.f, q0 = 0.f, s1 = 0.f, q1 = 0.f;
#pragma unroll
        for (int j = 0; j < 4; j++) {
          float hA = fmaxf(acc0[j] + bbA, 0.f);
          float hB = fmaxf(acc1[j] + bbB, 0.f);
          s0 += hA; q0 += hA * hA;
          s1 += hB; q1 += hB * hB;
        }
        s0 += __shfl_xor(s0, 16); s0 += __shfl_xor(s0, 32);
        q0 += __shfl_xor(q0, 16); q0 += __shfl_xor(q0, 32);
        s1 += __shfl_xor(s1, 16); s1 += __shfl_xor(s1, 32);
        q1 += __shfl_xor(q1, 16); q1 += __shfl_xor(q1, 32);
        if (g == 0) {
          st[v * 256 + cA] += s0; st[4352 + v * 256 + cA] += q0;
          st[v * 256 + cB] += s1; st[4352 + v * 256 + cB] += q1;
        }
      }
    }
    __syncthreads();
    for (int i = tid; i < 4352; i += 512) {
      size_t o = (size_t)blockIdx.x * 4352 + i;
      if (chunk == 0) { Ps3[o] = st[i]; Pq3[o] = st[4352 + i]; }
      else            { Ps3[o] += st[i]; Pq3[o] += st[4352 + i]; }
    }
    __syncthreads();
  }
}

// headk (tier-3): original fused head.
__global__ __launch_bounds__(256) void headk(const float* __restrict__ Ps3, const float* __restrict__ sc3,
                                             const float* __restrict__ sh3, const float* __restrict__ Wf,
                                             const float* __restrict__ bf_, float* __restrict__ out, int NS) {
  __shared__ float pl[C3];
  int b = blockIdx.x, tid = threadIdx.x;
  float a = 0.f, shs = 0.f;
#pragma unroll
  for (int v = 0; v < 17; v++) {
    float sbv = 0.f;
    for (int s2 = 0; s2 < NS; s2++) sbv += Ps3[(size_t)(b * NS + s2) * 4352 + v * 256 + tid];
    a += sc3[v * 256 + tid] * sbv;
    shs += sh3[v * 256 + tid];
  }
  pl[tid] = a * (1.f / 8704.f) + shs * (1.f / 17.f);
  __syncthreads();
  if (tid < NCLS) {
    float acc = bf_[tid];
#pragma unroll 4
    for (int cc = 0; cc < C3; cc++) acc += pl[cc] * Wf[cc * NCLS + tid];
    out[b * NCLS + tid] = acc;
  }
}

// ==================== fallback path (round-1 kernels, used if ws too small) ====================
enum : int {
  FO_N = 0, FO_SC1 = 289, FO_SH1 = FO_SC1 + NV * C1, FO_SC2 = FO_SH1 + NV * C1,
  FO_SH2 = FO_SC2 + NV * C2, FO_SC3 = FO_SH2 + NV * C2, FO_SH3 = FO_SC3 + NV * C3,
  FO_ACC = FO_SH3 + NV * C3, FO_SUM1 = FO_ACC, FO_SQ1 = FO_SUM1 + NV * C1,
  FO_SUM2 = FO_SQ1 + NV * C1, FO_SQ2 = FO_SUM2 + NV * C2, FO_SUM3 = FO_SQ2 + NV * C2,
  FO_SQ3 = FO_SUM3 + NV * C3, FO_S = FO_SQ3 + NV * C3, FO_END = FO_S + BB * NV * C3,
};

__global__ __launch_bounds__(64) void build_NF(const int* __restrict__ ei, float* __restrict__ Nout) {
  __shared__ float A[NV][NV];
  __shared__ float dinv[NV];
  int tid = threadIdx.x;
  for (int i = tid; i < NV * NV; i += 64) A[i / NV][i % NV] = 0.f;
  __syncthreads();
  if (tid == 0) {
    for (int e = 0; e < 36; e++) { int s = ei[e], d = ei[36 + e]; A[d][s] += 1.f; }
    for (int v = 0; v < NV; v++) A[v][v] += 1.f;
  }
  __syncthreads();
  if (tid < NV) {
    float s = 0.f;
    for (int u = 0; u < NV; u++) s += A[tid][u];
    dinv[tid] = rsqrtf(s);
  }
  __syncthreads();
  for (int i = tid; i < NV * NV; i += 64) Nout[i] = dinv[i / NV] * A[i / NV][i % NV] * dinv[i % NV];
}

__global__ __launch_bounds__(256) void pass1F(const float* __restrict__ x, const float* __restrict__ Nm,
                                              const float* __restrict__ W1, const float* __restrict__ b1,
                                              float* __restrict__ sum1, float* __restrict__ sq1) {
  __shared__ float Ns[NV * NV];
  __shared__ float xr[4][51];
  int tid = threadIdx.x;
  int c = tid & 63, ty = tid >> 6;
  for (int i = tid; i < NV * NV; i += 256) Ns[i] = Nm[i];
  float w0 = W1[c], w1 = W1[64 + c], w2 = W1[128 + c], bb = b1[c];
  float sacc[NV], qacc[NV];
#pragma unroll
  for (int v = 0; v < NV; v++) { sacc[v] = 0.f; qacc[v] = 0.f; }
  __syncthreads();
  int base = blockIdx.x * 32;
  for (int i = 0; i < 8; i++) {
    int r = base + ty + 4 * i;
    __syncthreads();
    for (int j = c; j < 51; j += 64) xr[ty][j] = x[r * 51 + j];
    __syncthreads();
    float y1r[NV];
#pragma unroll
    for (int u = 0; u < NV; u++)
      y1r[u] = xr[ty][u * 3] * w0 + xr[ty][u * 3 + 1] * w1 + xr[ty][u * 3 + 2] * w2;
#pragma unroll
    for (int v = 0; v < NV; v++) {
      float h = bb;
#pragma unroll
      for (int u = 0; u < NV; u++) h += Ns[v * NV + u] * y1r[u];
      h = fmaxf(h, 0.f);
      sacc[v] += h; qacc[v] += h * h;
    }
  }
#pragma unroll
  for (int v = 0; v < NV; v++) {
    atomicAdd(&sum1[v * 64 + c], sacc[v]);
    atomicAdd(&sq1[v * 64 + c], qacc[v]);
  }
}

__global__ __launch_bounds__(256) void finalize_bnF(const float* __restrict__ sum, const float* __restrict__ sq,
                                                    const float* __restrict__ g, const float* __restrict__ be,
                                                    float* __restrict__ sc, float* __restrict__ sh, int n) {
  int i = blockIdx.x * 256 + threadIdx.x;
  if (i < n) {
    float m = sum[i] * (1.f / 16384.f);
    float v = sq[i] * (1.f / 16384.f) - m * m;
    float r = rsqrtf(v + 1e-5f);
    float s = g[i] * r;
    sc[i] = s;
    sh[i] = be[i] - m * s;
  }
}

__global__ __launch_bounds__(128) void pass2F(const float* __restrict__ x, const float* __restrict__ Nm,
                                              const float* __restrict__ W1, const float* __restrict__ b1,
                                              const float* __restrict__ sc1, const float* __restrict__ sh1,
                                              const float* __restrict__ W2, const float* __restrict__ b2,
                                              float* __restrict__ sum2, float* __restrict__ sq2) {
  __shared__ float Ns[NV * NV];
  __shared__ float xr[51];
  __shared__ __align__(16) float y1[NV * C1];
  __shared__ __align__(16) float h1n[NV * C1];
  int tid = threadIdx.x;
  for (int i = tid; i < NV * NV; i += 128) Ns[i] = Nm[i];
  float bb = b2[tid];
  float sacc[NV], qacc[NV];
#pragma unroll
  for (int v = 0; v < NV; v++) { sacc[v] = 0.f; qacc[v] = 0.f; }
  __syncthreads();
  int base = blockIdx.x * 16;
  for (int i = 0; i < 16; i++) {
    int r = base + i;
    __syncthreads();
    if (tid < 51) xr[tid] = x[r * 51 + tid];
    __syncthreads();
    for (int idx = tid; idx < NV * C1; idx += 128) {
      int u = idx >> 6, cc = idx & 63;
      y1[idx] = xr[u * 3] * W1[cc] + xr[u * 3 + 1] * W1[64 + cc] + xr[u * 3 + 2] * W1[128 + cc];
    }
    __syncthreads();
    for (int idx = tid; idx < NV * C1; idx += 128) {
      int v = idx >> 6, cc = idx & 63;
      float h = b1[cc];
#pragma unroll
      for (int u = 0; u < NV; u++) h += Ns[v * NV + u] * y1[u * 64 + cc];
      h1n[idx] = fmaxf(h, 0.f) * sc1[idx] + sh1[idx];
    }
    __syncthreads();
    float y2r[NV];
#pragma unroll
    for (int u = 0; u < NV; u++) y2r[u] = 0.f;
#pragma unroll 2
    for (int k0 = 0; k0 < 64; k0 += 4) {
      float wa = W2[(k0)*128 + tid];
      float wb = W2[(k0 + 1) * 128 + tid];
      float wc = W2[(k0 + 2) * 128 + tid];
      float wd = W2[(k0 + 3) * 128 + tid];
#pragma unroll
      for (int u = 0; u < NV; u++) {
        float4 h4 = *reinterpret_cast<const float4*>(&h1n[u * 64 + k0]);
        y2r[u] += h4.x * wa + h4.y * wb + h4.z * wc + h4.w * wd;
      }
    }
#pragma unroll
    for (int v = 0; v < NV; v++) {
      float h = bb;
#pragma unroll
      for (int u = 0; u < NV; u++) h += Ns[v * NV + u] * y2r[u];
      h = fmaxf(h, 0.f);
      sacc[v] += h; qacc[v] += h * h;
    }
  }
#pragma unroll
  for (int v = 0; v < NV; v++) {
    atomicAdd(&sum2[v * 128 + tid], sacc[v]);
    atomicAdd(&sq2[v * 128 + tid], qacc[v]);
  }
}

__global__ __launch_bounds__(128) void pass3F(const float* __restrict__ x, const float* __restrict__ Nm,
                                              const float* __restrict__ W1, const float* __restrict__ b1,
                                              const float* __restrict__ sc1, const float* __restrict__ sh1,
                                              const float* __restrict__ W2, const float* __restrict__ b2,
                                              const float* __restrict__ sc2, const float* __restrict__ sh2,
                                              const float* __restrict__ W3, const float* __restrict__ b3,
                                              float* __restrict__ sum3, float* __restrict__ sq3,
                                              float* __restrict__ S) {
  __shared__ float Ns[NV * NV];
  __shared__ float xr[51];
  __shared__ __align__(16) float y1[NV * C1];
  __shared__ __align__(16) float h1n[NV * C1];
  __shared__ __align__(16) float h2n[NV * C2];
  int tid = threadIdx.x;
  int b = blockIdx.x >> 5, chunk = blockIdx.x & 31;
  int rbase = b * TT + chunk * 16;
  for (int i = tid; i < NV * NV; i += 128) Ns[i] = Nm[i];
  float bb2 = b2[tid];
  float b3a = b3[tid], b3b = b3[tid + 128];
  float sA[NV], qA[NV], sB[NV], qB[NV];
#pragma unroll
  for (int v = 0; v < NV; v++) { sA[v] = 0.f; qA[v] = 0.f; sB[v] = 0.f; qB[v] = 0.f; }
  __syncthreads();
  for (int i = 0; i < 16; i++) {
    int r = rbase + i;
    __syncthreads();
    if (tid < 51) xr[tid] = x[r * 51 + tid];
    __syncthreads();
    for (int idx = tid; idx < NV * C1; idx += 128) {
      int u = idx >> 6, cc = idx & 63;
      y1[idx] = xr[u * 3] * W1[cc] + xr[u * 3 + 1] * W1[64 + cc] + xr[u * 3 + 2] * W1[128 + cc];
    }
    __syncthreads();
    for (int idx = tid; idx < NV * C1; idx += 128) {
      int v = idx >> 6, cc = idx & 63;
      float h = b1[cc];
#pragma unroll
      for (int u = 0; u < NV; u++) h += Ns[v * NV + u] * y1[u * 64 + cc];
      h1n[idx] = fmaxf(h, 0.f) * sc1[idx] + sh1[idx];
    }
    __syncthreads();
    {
      float y2r[NV];
#pragma unroll
      for (int u = 0; u < NV; u++) y2r[u] = 0.f;
#pragma unroll 2
      for (int k0 = 0; k0 < 64; k0 += 4) {
        float wa = W2[(k0)*128 + tid];
        float wb = W2[(k0 + 1) * 128 + tid];
        float wc = W2[(k0 + 2) * 128 + tid];
        float wd = W2[(k0 + 3) * 128 + tid];
#pragma unroll
        for (int u = 0; u < NV; u++) {
          float4 h4 = *reinterpret_cast<const float4*>(&h1n[u * 64 + k0]);
          y2r[u] += h4.x * wa + h4.y * wb + h4.z * wc + h4.w * wd;
        }
      }
#pragma unroll
      for (int v = 0; v < NV; v++) {
        float h = bb2;
#pragma unroll
        for (int u = 0; u < NV; u++) h += Ns[v * NV + u] * y2r[u];
        int e = v * 128 + tid;
        h2n[e] = fmaxf(h, 0.f) * sc2[e] + sh2[e];
      }
    }
    __syncthreads();
    float y3a[NV], y3b[NV];
#pragma unroll
    for (int u = 0; u < NV; u++) { y3a[u] = 0.f; y3b[u] = 0.f; }
#pragma unroll 2
    for (int k0 = 0; k0 < 128; k0 += 4) {
      float wa0 = W3[(k0)*256 + tid], wb0 = W3[(k0)*256 + 128 + tid];
      float wa1 = W3[(k0 + 1) * 256 + tid], wb1 = W3[(k0 + 1) * 256 + 128 + tid];
      float wa2 = W3[(k0 + 2) * 256 + tid], wb2 = W3[(k0 + 2) * 256 + 128 + tid];
      float wa3 = W3[(k0 + 3) * 256 + tid], wb3 = W3[(k0 + 3) * 256 + 128 + tid];
#pragma unroll
      for (int u = 0; u < NV; u++) {
        float4 h4 = *reinterpret_cast<const float4*>(&h2n[u * 128 + k0]);
        y3a[u] += h4.x * wa0 + h4.y * wa1 + h4.z * wa2 + h4.w * wa3;
        y3b[u] += h4.x * wb0 + h4.y * wb1 + h4.z * wb2 + h4.w * wb3;
      }
    }
#pragma unroll
    for (int v = 0; v < NV; v++) {
      float ha = b3a, hb = b3b;
#pragma unroll
      for (int u = 0; u < NV; u++) {
        float nn = Ns[v * NV + u];
        ha += nn * y3a[u];
        hb += nn * y3b[u];
      }
      ha = fmaxf(ha, 0.f); hb = fmaxf(hb, 0.f);
      sA[v] += ha; qA[v] += ha * ha;
      sB[v] += hb; qB[v] += hb * hb;
    }
  }
#pragma unroll
  for (int v = 0; v < NV; v++) {
    int ea = v * 256 + tid, eb = ea + 128;
    atomicAdd(&sum3[ea], sA[v]); atomicAdd(&sq3[ea], qA[v]);
    atomicAdd(&sum3[eb], sB[v]); atomicAdd(&sq3[eb], qB[v]);
    atomicAdd(&S[b * (NV * C3) + ea], sA[v]);
    atomicAdd(&S[b * (NV * C3) + eb], sB[v]);
  }
}

__global__ __launch_bounds__(256) void headF(const float* __restrict__ S, const float* __restrict__ sc3,
                                             const float* __restrict__ sh3, const float* __restrict__ Wf,
                                             const float* __restrict__ bf, float* __restrict__ out) {
  __shared__ float pl[C3];
  int b = blockIdx.x, tid = threadIdx.x;
  float a = 0.f, sh = 0.f;
#pragma unroll
  for (int v = 0; v < NV; v++) {
    int e = v * 256 + tid;
    a += S[b * (NV * C3) + e] * sc3[e];
    sh += sh3[e];
  }
  pl[tid] = a * (1.f / 8704.f) + sh * (1.f / 17.f);
  __syncthreads();
  if (tid < NCLS) {
    float acc = bf[tid];
#pragma unroll 4
    for (int c = 0; c < C3; c++) acc += pl[c] * Wf[c * NCLS + tid];
    out[b * NCLS + tid] = acc;
  }
}

extern "C" void kernel_launch(void* const* d_in, const int* in_sizes, int n_in,
                              void* d_out, int out_size, void* d_ws, size_t ws_size,
                              hipStream_t stream) {
  (void)in_sizes; (void)n_in; (void)out_size;
  const float* x   = (const float*)d_in[0];
  const int*   ei  = (const int*)d_in[1];
  const float* W1  = (const float*)d_in[2];
  const float* b1  = (const float*)d_in[3];
  const float* g1  = (const float*)d_in[4];
  const float* be1 = (const float*)d_in[5];
  const float* W2  = (const float*)d_in[6];
  const float* b2  = (const float*)d_in[7];
  const float* g2  = (const float*)d_in[8];
  const float* be2 = (const float*)d_in[9];
  const float* W3  = (const float*)d_in[10];
  const float* b3  = (const float*)d_in[11];
  const float* g3  = (const float*)d_in[12];
  const float* be3 = (const float*)d_in[13];
  const float* Wf  = (const float*)d_in[14];
  const float* bf  = (const float*)d_in[15];
  float* ws = (float*)d_ws;

  if (ws_size >= (size_t)T4_END * sizeof(float)) {
    // -------- tier-4 (R10): non-temporal streams --------
    build_Npad<<<1, 64, 0, stream>>>(ei, ws + T4_N);
    repackk<<<160, 256, 0, stream>>>(W2, W3, (short*)(ws + T4_W2P), (short*)(ws + T4_W3P));
    pass1w<<<512, 512, 0, stream>>>(x, ws + T4_N, W1, b1, ws + T4_H1);
    stats1k<<<512, 512, 0, stream>>>(ws + T4_H1, ws + T4_PS1, ws + T4_PQ1);
    finalize_k<<<17, 1024, 0, stream>>>(ws + T4_PS1, ws + T4_PQ1, 512, 1088, g1, be1, ws + T4_SC1, ws + T4_SH1);
    pass2g<<<1024, 512, 0, stream>>>(ws + T4_H1, ws + T4_N, ws + T4_SC1, ws + T4_SH1,
                                     (const short*)(ws + T4_W2P), b2, ws + T4_PS3, ws + T4_PQ3,
                                     (unsigned int*)(ws + T4_H2));
    finalize_k<<<34, 1024, 0, stream>>>(ws + T4_PS3, ws + T4_PQ3, 1024, 2176, g2, be2, ws + T4_SC2, ws + T4_SH2);
    pass3h<<<1024, 512, 0, stream>>>((const unsigned int*)(ws + T4_H2), ws + T4_N,
                                     ws + T4_SC2, ws + T4_SH2,
                                     (const short*)(ws + T4_W3P), b3, ws + T4_PS3, ws + T4_PQ3);
    finalize_k<<<68, 1024, 0, stream>>>(ws + T4_PS3, ws + T4_PQ3, 1024, 4352, g3, be3, ws + T4_SC3, ws + T4_SH3);
    head1<<<256, 256, 0, stream>>>(ws + T4_PS3, ws + T4_SC3, ws + T4_PP);
    head2<<<BB, 256, 0, stream>>>(ws + T4_PP, ws + T4_SH3, Wf, bf, (float*)d_out);
  } else if (ws_size >= (size_t)T3_END * sizeof(float)) {
    // -------- tier-3: H1-dedup path --------
    build_Npad<<<1, 64, 0, stream>>>(ei, ws + T3_N);
    repackk<<<160, 256, 0, stream>>>(W2, W3, (short*)(ws + T3_W2P), (short*)(ws + T3_W3P));
    pass1k<<<512, 512, 0, stream>>>(x, ws + T3_N, W1, b1, ws + T3_PS1, ws + T3_PQ1, ws + T3_H1);
    finalize_k<<<17, 1024, 0, stream>>>(ws + T3_PS1, ws + T3_PQ1, 512, 1088, g1, be1, ws + T3_SC1, ws + T3_SH1);
    pass2h<<<512, 512, 0, stream>>>(ws + T3_H1, ws + T3_N, ws + T3_SC1, ws + T3_SH1,
                                    (const short*)(ws + T3_W2P), b2, ws + T3_PS2, ws + T3_PQ2, ws + T3_M1);
    finalize_k<<<34, 1024, 0, stream>>>(ws + T3_PS2, ws + T3_PQ2, 512, 2176, g2, be2, ws + T3_SC2, ws + T3_SH2);
    pass3r<<<1024, 512, 0, stream>>>(ws + T3_M1, ws + T3_N,
                                     (const short*)(ws + T3_W2P), b2, ws + T3_SC2, ws + T3_SH2,
                                     (const short*)(ws + T3_W3P), b3, ws + T3_PS3, ws + T3_PQ3, 1);
    finalize_k<<<68, 1024, 0, stream>>>(ws + T3_PS3, ws + T3_PQ3, 1024, 4352, g3, be3, ws + T3_SC3, ws + T3_SH3);
    headk<<<BB, 256, 0, stream>>>(ws + T3_PS3, ws + T3_SC3, ws + T3_SH3, Wf, bf, (float*)d_out, 32);
  } else {
    // -------- fallback (round-1 scalar path) --------
    float* Nm   = ws + FO_N;
    float* sc1  = ws + FO_SC1; float* sh1 = ws + FO_SH1;
    float* sc2  = ws + FO_SC2; float* sh2 = ws + FO_SH2;
    float* sc3  = ws + FO_SC3; float* sh3 = ws + FO_SH3;
    float* sum1 = ws + FO_SUM1; float* sq1 = ws + FO_SQ1;
    float* sum2 = ws + FO_SUM2; float* sq2 = ws + FO_SQ2;
    float* sum3 = ws + FO_SUM3; float* sq3 = ws + FO_SQ3;
    float* S    = ws + FO_S;

    hipMemsetAsync(ws + FO_ACC, 0, (size_t)(FO_END - FO_ACC) * sizeof(float), stream);
    build_NF<<<1, 64, 0, stream>>>(ei, Nm);
    pass1F<<<512, 256, 0, stream>>>(x, Nm, W1, b1, sum1, sq1);
    finalize_bnF<<<(NV * C1 + 255) / 256, 256, 0, stream>>>(sum1, sq1, g1, be1, sc1, sh1, NV * C1);
    pass2F<<<1024, 128, 0, stream>>>(x, Nm, W1, b1, sc1, sh1, W2, b2, sum2, sq2);
    finalize_bnF<<<(NV * C2 + 255) / 256, 256, 0, stream>>>(sum2, sq2, g2, be2, sc2, sh2, NV * C2);
    pass3F<<<1024, 128, 0, stream>>>(x, Nm, W1, b1, sc1, sh1, W2, b2, sc2, sh2, W3, b3, sum3, sq3, S);
    finalize_bnF<<<(NV * C3 + 255) / 256, 256, 0, stream>>>(sum3, sq3, g3, be3, sc3, sh3, NV * C3);
    headF<<<BB, 256, 0, stream>>>(S, sc3, sh3, Wf, bf, (float*)d_out);
  }
}

// Round 12
// 266.403 us; speedup vs baseline: 1.1764x; 1.1764x over previous
//
#include <hip/hip_runtime.h>
#include <hip/hip_bf16.h>

#define BB 32
#define TT 512
#define NV 17
#define C1 64
#define C2 128
#define C3 256
#define NCLS 60

typedef __attribute__((ext_vector_type(8))) short bf16x8;
typedef __attribute__((ext_vector_type(4))) float f32x4;
#define MFMA16(a, b, c) __builtin_amdgcn_mfma_f32_16x16x32_bf16((a), (b), (c), 0, 0, 0)

__device__ __forceinline__ float bf2f(unsigned int u16) {
  union { unsigned int i; float f; } c; c.i = (u16 & 0xffffu) << 16; return c.f;
}
__device__ __forceinline__ unsigned int f2bf(float f) {
  union { float f; unsigned int i; } c; c.f = f;
  unsigned int u = c.i;
  u = (u + 0x7fffu + ((u >> 16) & 1u)) >> 16;
  return u & 0xffffu;
}
__device__ __forceinline__ bf16x8 afrag(const short* buf, int byteoff) {
  return *reinterpret_cast<const bf16x8*>(reinterpret_cast<const char*>(buf) + byteoff);
}

// ---------------- tier-3 (R4) ws layout ----------------
enum : int {
  T3_N    = 0,
  T3_SC1  = 384,
  T3_SH1  = 1472,
  T3_SC2  = 2560,
  T3_SH2  = 4736,
  T3_SC3  = 6912,
  T3_SH3  = 11264,
  T3_W2P  = 15616,
  T3_W3P  = 19712,
  T3_PS1  = 36096,
  T3_PQ1  = 593152,
  T3_PS2  = 1150208,
  T3_PQ2  = 2264320,
  T3_PS3  = 3378432,      // 1024*4352
  T3_PQ3  = 7834880,
  T3_M1   = 12291328,     // 1024*8704
  T3_H1   = 21204224,     // 16384*1088
  T3_END  = 39030016,     // ~156.1 MB
};

// ---------------- tier-4 ws layout: H1 (f32) + H2 (bf16 [tile][p][v][tid]) ----
enum : int {
  T4_N    = 0,
  T4_SC1  = 384,
  T4_SH1  = 1472,
  T4_SC2  = 2560,
  T4_SH2  = 4736,
  T4_SC3  = 6912,
  T4_SH3  = 11264,
  T4_W2P  = 15616,
  T4_W3P  = 19712,
  T4_PS1  = 36096,
  T4_PQ1  = 593152,
  T4_PP   = 1150208,      // head1 partials: 256 blocks * 256 floats
  T4_PQ2  = 2264320,
  T4_PS3  = 3378432,      // 1024*4352 (also pass2g partial scratch)
  T4_PQ3  = 7834880,
  T4_H1   = 12291328,     // 16384*1088 f32
  T4_H2   = 30117120,     // 1024 tiles * 2p * 17v * 512 short2 (71.3MB)
  T4_END  = 47942912,     // ~191.8 MB
};

__global__ __launch_bounds__(64) void build_Npad(const int* __restrict__ ei, float* __restrict__ Nout) {
  __shared__ float A[NV][NV];
  __shared__ float dinv[NV];
  int tid = threadIdx.x;
  for (int i = tid; i < NV * NV; i += 64) A[i / NV][i % NV] = 0.f;
  __syncthreads();
  if (tid == 0) {
    for (int e = 0; e < 36; e++) {
      int s = ei[e], d = ei[36 + e];
      A[d][s] += 1.f;
    }
    for (int v = 0; v < NV; v++) A[v][v] += 1.f;
  }
  __syncthreads();
  if (tid < NV) {
    float s = 0.f;
    for (int u = 0; u < NV; u++) s += A[tid][u];
    dinv[tid] = rsqrtf(s);
  }
  __syncthreads();
  for (int i = tid; i < 340; i += 64) {
    int v = i / 20, u = i % 20;
    Nout[i] = (u < NV) ? dinv[v] * A[v][u] * dinv[u] : 0.f;
  }
}

// repack W2 [64][128] and W3 [128][256] fp32 into bf16 MFMA B-fragments.
__global__ __launch_bounds__(256) void repackk(const float* __restrict__ W2, const float* __restrict__ W3,
                                               short* __restrict__ W2p, short* __restrict__ W3p) {
  int id = blockIdx.x * 256 + threadIdx.x;
  if (id < 8192) {
    int e = id & 7, lane = (id >> 3) & 63, fid = id >> 9;
    int nt = fid >> 1, ks = fid & 1;
    int k = ks * 32 + (lane >> 4) * 8 + e, n = nt * 16 + (lane & 15);
    W2p[id] = (short)f2bf(W2[k * 128 + n]);
  } else if (id < 40960) {
    int j = id - 8192;
    int e = j & 7, lane = (j >> 3) & 63, fid = j >> 9;
    int nt = fid >> 2, ks = fid & 3;
    int k = ks * 32 + (lane >> 4) * 8 + e, n = nt * 16 + (lane & 15);
    W3p[j] = (short)f2bf(W3[k * 256 + n]);
  }
}

// pass1w (tier-4): mix1 -> H1 ONLY.
__global__ __launch_bounds__(512) void pass1w(const float* __restrict__ x, const float* __restrict__ Nw,
                                              const float* __restrict__ W1, const float* __restrict__ b1,
                                              float* __restrict__ H1o) {
  __shared__ float xr[32][52];
  __shared__ float Ns[340];
  __shared__ float W1s[192];
  __shared__ float b1s[64];
  int tid = threadIdx.x;
  for (int i = tid; i < 340; i += 512) Ns[i] = Nw[i];
  for (int i = tid; i < 192; i += 512) W1s[i] = W1[i];
  if (tid < 64) b1s[tid] = b1[tid];
  int rbase = blockIdx.x * 32;
  for (int i = tid; i < 32 * 51; i += 512) xr[i / 51][i % 51] = x[(size_t)(rbase + i / 51) * 51 + i % 51];
  int c2 = tid & 31, rg = tid >> 5;
  int c = c2 * 2;
  __syncthreads();
  float w1a0 = W1s[c], w1a1 = W1s[c + 1];
  float w1b0 = W1s[64 + c], w1b1 = W1s[64 + c + 1];
  float w1c0 = W1s[128 + c], w1c1 = W1s[128 + c + 1];
  float bb0 = b1s[c], bb1 = b1s[c + 1];
#pragma unroll 1
  for (int rr = 0; rr < 2; rr++) {
    int r = rg + rr * 16;
    float y0[17], y1v[17];
#pragma unroll
    for (int u = 0; u < 17; u++) {
      float xa = xr[r][u * 3], xb = xr[r][u * 3 + 1], xc = xr[r][u * 3 + 2];
      y0[u] = xa * w1a0 + xb * w1b0 + xc * w1c0;
      y1v[u] = xa * w1a1 + xb * w1b1 + xc * w1c1;
    }
#pragma unroll
    for (int v = 0; v < 17; v++) {
      float a0 = 0.f, a1 = 0.f;
#pragma unroll
      for (int u0 = 0; u0 < 16; u0 += 4) {
        float4 n4 = *reinterpret_cast<const float4*>(&Ns[v * 20 + u0]);
        a0 += n4.x * y0[u0] + n4.y * y0[u0 + 1] + n4.z * y0[u0 + 2] + n4.w * y0[u0 + 3];
        a1 += n4.x * y1v[u0] + n4.y * y1v[u0 + 1] + n4.z * y1v[u0 + 2] + n4.w * y1v[u0 + 3];
      }
      float n16 = Ns[v * 20 + 16];
      a0 += n16 * y0[16]; a1 += n16 * y1v[16];
      float h0 = fmaxf(a0 + bb0, 0.f), h1 = fmaxf(a1 + bb1, 0.f);
      *reinterpret_cast<float2*>(&H1o[(size_t)(rbase + r) * 1088 + v * 64 + c]) = make_float2(h0, h1);
    }
  }
}

// stats1k (tier-4): stream H1, per-block (32 rows) channel sums -> Ps1/Pq1.
__global__ __launch_bounds__(512) void stats1k(const float* __restrict__ H1,
                                               float* __restrict__ Ps1, float* __restrict__ Pq1) {
  const int tid = threadIdx.x;
  const size_t rbase = (size_t)blockIdx.x * 32;
  for (int ch = tid; ch < 1088; ch += 512) {
    float s = 0.f, q = 0.f;
#pragma unroll 4
    for (int r = 0; r < 32; r++) {
      float v = H1[(rbase + r) * 1088 + ch];
      s += v; q += v * v;
    }
    Ps1[(size_t)blockIdx.x * 1088 + ch] = s;
    Pq1[(size_t)blockIdx.x * 1088 + ch] = q;
  }
}

// pass1k (tier-3): stats of relu(N(xW1)+b1); saves h1.
__global__ __launch_bounds__(512) void pass1k(const float* __restrict__ x, const float* __restrict__ Nw,
                                              const float* __restrict__ W1, const float* __restrict__ b1,
                                              float* __restrict__ Ps1, float* __restrict__ Pq1,
                                              float* __restrict__ H1o) {
  __shared__ float scratch[16 * 17 * 64];
  __shared__ float xr[32][52];
  __shared__ float Ns[340];
  __shared__ float W1s[192];
  __shared__ float b1s[64];
  int tid = threadIdx.x;
  const bool saveH = (H1o != nullptr);
  for (int i = tid; i < 340; i += 512) Ns[i] = Nw[i];
  for (int i = tid; i < 192; i += 512) W1s[i] = W1[i];
  if (tid < 64) b1s[tid] = b1[tid];
  int rbase = blockIdx.x * 32;
  for (int i = tid; i < 32 * 51; i += 512) xr[i / 51][i % 51] = x[(size_t)(rbase + i / 51) * 51 + i % 51];
  int c2 = tid & 31, rg = tid >> 5;
  int c = c2 * 2;
  float s0[17], s1[17], q0[17], q1[17];
#pragma unroll
  for (int v = 0; v < 17; v++) { s0[v] = 0.f; s1[v] = 0.f; q0[v] = 0.f; q1[v] = 0.f; }
  __syncthreads();
  float w1a0 = W1s[c], w1a1 = W1s[c + 1];
  float w1b0 = W1s[64 + c], w1b1 = W1s[64 + c + 1];
  float w1c0 = W1s[128 + c], w1c1 = W1s[128 + c + 1];
  float bb0 = b1s[c], bb1 = b1s[c + 1];
  for (int rr = 0; rr < 2; rr++) {
    int r = rg + rr * 16;
    float y0[17], y1v[17];
#pragma unroll
    for (int u = 0; u < 17; u++) {
      float xa = xr[r][u * 3], xb = xr[r][u * 3 + 1], xc = xr[r][u * 3 + 2];
      y0[u] = xa * w1a0 + xb * w1b0 + xc * w1c0;
      y1v[u] = xa * w1a1 + xb * w1b1 + xc * w1c1;
    }
#pragma unroll
    for (int v = 0; v < 17; v++) {
      float a0 = 0.f, a1 = 0.f;
#pragma unroll
      for (int u0 = 0; u0 < 16; u0 += 4) {
        float4 n4 = *reinterpret_cast<const float4*>(&Ns[v * 20 + u0]);
        a0 += n4.x * y0[u0] + n4.y * y0[u0 + 1] + n4.z * y0[u0 + 2] + n4.w * y0[u0 + 3];
        a1 += n4.x * y1v[u0] + n4.y * y1v[u0 + 1] + n4.z * y1v[u0 + 2] + n4.w * y1v[u0 + 3];
      }
      float n16 = Ns[v * 20 + 16];
      a0 += n16 * y0[16]; a1 += n16 * y1v[16];
      float h0 = fmaxf(a0 + bb0, 0.f), h1 = fmaxf(a1 + bb1, 0.f);
      if (saveH)
        *reinterpret_cast<float2*>(&H1o[(size_t)(rbase + r) * 1088 + v * 64 + c]) = make_float2(h0, h1);
      s0[v] += h0; q0[v] += h0 * h0;
      s1[v] += h1; q1[v] += h1 * h1;
    }
  }
#pragma unroll
  for (int v = 0; v < 17; v++)
    *reinterpret_cast<float2*>(&scratch[(rg * 17 + v) * 64 + c]) = make_float2(s0[v], s1[v]);
  __syncthreads();
  for (int i = tid; i < 1088; i += 512) {
    float a = 0.f;
#pragma unroll
    for (int r2 = 0; r2 < 16; r2++) a += scratch[(r2 * 17 + (i >> 6)) * 64 + (i & 63)];
    Ps1[(size_t)blockIdx.x * 1088 + i] = a;
  }
  __syncthreads();
#pragma unroll
  for (int v = 0; v < 17; v++)
    *reinterpret_cast<float2*>(&scratch[(rg * 17 + v) * 64 + c]) = make_float2(q0[v], q1[v]);
  __syncthreads();
  for (int i = tid; i < 1088; i += 512) {
    float a = 0.f;
#pragma unroll
    for (int r2 = 0; r2 < 16; r2++) a += scratch[(r2 * 17 + (i >> 6)) * 64 + (i & 63)];
    Pq1[(size_t)blockIdx.x * 1088 + i] = a;
  }
}

// finalize BN: sum partials -> scale/shift. Variable block size (ng = blockDim/64
// p-stride groups); launched at 1024 threads for 4x more latency-hiding waves.
__global__ __launch_bounds__(1024) void finalize_k(const float* __restrict__ Ps, const float* __restrict__ Pq,
                                                   int P, int C, const float* __restrict__ g,
                                                   const float* __restrict__ be, float* __restrict__ sc,
                                                   float* __restrict__ sh) {
  __shared__ float rs[16][64], rq[16][64];
  int l = threadIdx.x & 63, w = threadIdx.x >> 6;
  int ng = blockDim.x >> 6;
  int i = blockIdx.x * 64 + l;
  float s = 0.f, q = 0.f;
  if (i < C) {
    for (int p = w; p < P; p += ng) { s += Ps[(size_t)p * C + i]; q += Pq[(size_t)p * C + i]; }
  }
  rs[w][l] = s; rq[w][l] = q;
  __syncthreads();
  if (w == 0 && i < C) {
    s = 0.f; q = 0.f;
    for (int t = 0; t < ng; t++) { s += rs[t][l]; q += rq[t][l]; }
    float m = s * (1.f / 16384.f);
    float var = q * (1.f / 16384.f) - m * m;
    float r = rsqrtf(var + 1e-5f);
    sc[i] = g[i] * r;
    sh[i] = be[i] - m * g[i] * r;
  }
}

// pass2g (tier-4): grid 1024, ONE 16-row tile per block. Stream h1 -> BN1 affine
// -> mix2 -> m1A -> W2-MFMA -> stats partials AND store H2 bf16 [tile][p][v][tid].
__global__ __launch_bounds__(512) void pass2g(const float* __restrict__ H1, const float* __restrict__ Nw,
                                              const float* __restrict__ sc1, const float* __restrict__ sh1,
                                              const short* __restrict__ W2p, const float* __restrict__ b2,
                                              float* __restrict__ Ps2, float* __restrict__ Pq2,
                                              short* __restrict__ H2) {
  __shared__ __align__(16) short m1A[17408];
  __shared__ float stats[4352];
  __shared__ float Ns[340];
  __shared__ float b2s[128];
  __shared__ float sc1s[1088], sh1s[1088];
  const int tid = threadIdx.x;
  const int lane = tid & 63, w = tid >> 6;
  const int row = lane & 15, g = lane >> 4;
  for (int i = tid; i < 340; i += 512) Ns[i] = Nw[i];
  if (tid < 128) b2s[tid] = b2[tid];
  for (int i = tid; i < 1088; i += 512) { sc1s[i] = sc1[i]; sh1s[i] = sh1[i]; }
  bf16x8 w2f0 = *reinterpret_cast<const bf16x8*>(&W2p[((w * 2 + 0) * 64 + lane) * 8]);
  bf16x8 w2f1 = *reinterpret_cast<const bf16x8*>(&W2p[((w * 2 + 1) * 64 + lane) * 8]);
  const int r_mix = tid >> 5;
  const int c2 = tid & 31;
  const int c = c2 * 2;
  short2* H2p = reinterpret_cast<short2*>(H2);
  const int tile = blockIdx.x;
  const int rbase = blockIdx.x * 16;
  __syncthreads();
  {
    const float* hrow = H1 + (size_t)(rbase + r_mix) * 1088;
    float t0[17], t1[17];
#pragma unroll
    for (int v = 0; v < 17; v++) {
      float2 hv = *reinterpret_cast<const float2*>(&hrow[v * 64 + c]);
      float2 scv = *reinterpret_cast<const float2*>(&sc1s[v * 64 + c]);
      float2 shv = *reinterpret_cast<const float2*>(&sh1s[v * 64 + c]);
      t0[v] = hv.x * scv.x + shv.x;
      t1[v] = hv.y * scv.y + shv.y;
    }
#pragma unroll
    for (int v = 0; v < 17; v++) {
      float a0 = 0.f, a1 = 0.f;
#pragma unroll
      for (int u0 = 0; u0 < 16; u0 += 4) {
        float4 n4 = *reinterpret_cast<const float4*>(&Ns[v * 20 + u0]);
        a0 += n4.x * t0[u0] + n4.y * t0[u0 + 1] + n4.z * t0[u0 + 2] + n4.w * t0[u0 + 3];
        a1 += n4.x * t1[u0] + n4.y * t1[u0 + 1] + n4.z * t1[u0 + 2] + n4.w * t1[u0 + 3];
      }
      float n16 = Ns[v * 20 + 16];
      a0 += n16 * t0[16]; a1 += n16 * t1[16];
      unsigned int pk = (f2bf(a1) << 16) | f2bf(a0);
      int off = v * 2048 + r_mix * 128 + ((c2 * 4) ^ ((r_mix & 7) << 4));
      *reinterpret_cast<unsigned int*>(reinterpret_cast<char*>(m1A) + off) = pk;
    }
  }
  __syncthreads();
#pragma unroll 1
  for (int v = 0; v < 17; v++) {
    int ab = v * 2048 + row * 128;
    int sw = (row & 7) << 4;
    bf16x8 a0 = afrag(m1A, ab + ((g * 16) ^ sw));
    bf16x8 a1 = afrag(m1A, ab + ((64 + g * 16) ^ sw));
    f32x4 acc = {0.f, 0.f, 0.f, 0.f};
    acc = MFMA16(a0, w2f0, acc);
    acc = MFMA16(a1, w2f1, acc);
    int cc = w * 16 + row;
    float bb = b2s[cc];
    float hj0 = fmaxf(acc[0] + bb, 0.f);
    float hj1 = fmaxf(acc[1] + bb, 0.f);
    float hj2 = fmaxf(acc[2] + bb, 0.f);
    float hj3 = fmaxf(acc[3] + bb, 0.f);
    short2 e0, e1;
    e0.x = (short)f2bf(hj0); e0.y = (short)f2bf(hj1);
    e1.x = (short)f2bf(hj2); e1.y = (short)f2bf(hj3);
    H2p[(((size_t)tile * 2 + 0) * 17 + v) * 512 + tid] = e0;
    H2p[(((size_t)tile * 2 + 1) * 17 + v) * 512 + tid] = e1;
    float s = hj0 + hj1 + hj2 + hj3;
    float q = hj0 * hj0 + hj1 * hj1 + hj2 * hj2 + hj3 * hj3;
    s += __shfl_xor(s, 16); s += __shfl_xor(s, 32);
    q += __shfl_xor(q, 16); q += __shfl_xor(q, 32);
    if (g == 0) {
      stats[v * 128 + cc] = s;
      stats[2176 + v * 128 + cc] = q;
    }
  }
  __syncthreads();
  for (int i = tid; i < 2176; i += 512) {
    Ps2[(size_t)blockIdx.x * 2176 + i] = stats[i];
    Pq2[(size_t)blockIdx.x * 2176 + i] = stats[2176 + i];
  }
}

// pass3h (tier-4): accumulate-into-outputs mix3 (o0/o1[17], no spill).
__global__ __launch_bounds__(512) void pass3h(const short* __restrict__ H2, const float* __restrict__ Nw,
                                              const float* __restrict__ sc2, const float* __restrict__ sh2,
                                              const short* __restrict__ W3p, const float* __restrict__ b3,
                                              float* __restrict__ Ps3, float* __restrict__ Pq3) {
  __shared__ __align__(16) short M2S[34816];    // m2A [17][16][128] bf16, swizzled
  __shared__ float Ns[340];
  __shared__ float b3s[256];
  const int tid = threadIdx.x;
  const int lane = tid & 63, w = tid >> 6;
  const int row = lane & 15, g = lane >> 4;
  const int cc = w * 16 + row;
  const int tile = blockIdx.x;
  const short2* H2p = reinterpret_cast<const short2*>(H2);
  for (int i = tid; i < 340; i += 512) Ns[i] = Nw[i];
  if (tid < 256) b3s[tid] = b3[tid];
  __syncthreads();
  const int sw = (row & 7) << 4;
#pragma unroll 1
  for (int p = 0; p < 2; p++) {
    float o0[17], o1[17];
#pragma unroll
    for (int vp = 0; vp < 17; vp++) { o0[vp] = 0.f; o1[vp] = 0.f; }
#pragma unroll 1
    for (int v = 0; v < 17; v++) {
      short2 hv = H2p[(((size_t)tile * 2 + p) * 17 + v) * 512 + tid];
      float scv = sc2[v * 128 + cc], shv = sh2[v * 128 + cc];
      float t0 = bf2f((unsigned int)hv.x) * scv + shv;
      float t1 = bf2f((unsigned int)hv.y) * scv + shv;
#pragma unroll
      for (int vp = 0; vp < 17; vp++) {
        float n = Ns[vp * 20 + v];
        o0[vp] += n * t0;
        o1[vp] += n * t1;
      }
    }
    const int r0 = 4 * g + 2 * p, r1 = r0 + 1;
    const int sw0 = (r0 & 7) << 4, sw1 = (r1 & 7) << 4;
#pragma unroll
    for (int vp = 0; vp < 17; vp++) {
      *reinterpret_cast<short*>(reinterpret_cast<char*>(M2S) + vp * 4096 + r0 * 256 + ((cc * 2) ^ sw0)) =
          (short)f2bf(o0[vp]);
      *reinterpret_cast<short*>(reinterpret_cast<char*>(M2S) + vp * 4096 + r1 * 256 + ((cc * 2) ^ sw1)) =
          (short)f2bf(o1[vp]);
    }
  }
  __syncthreads();
  {
    int z3 = 0;
    asm volatile("" : "+v"(z3));
    bf16x8 w3f0[4], w3f1[4];
#pragma unroll
    for (int ks = 0; ks < 4; ks++) {
      w3f0[ks] = *reinterpret_cast<const bf16x8*>(&W3p[(((w * 2 + 0) * 4 + ks) * 64 + lane) * 8 + z3]);
      w3f1[ks] = *reinterpret_cast<const bf16x8*>(&W3p[(((w * 2 + 1) * 4 + ks) * 64 + lane) * 8 + z3]);
    }
#pragma unroll 1
    for (int v = 0; v < 17; v++) {
      int ab = v * 4096 + row * 256;
      bf16x8 a[4];
#pragma unroll
      for (int ks = 0; ks < 4; ks++) a[ks] = afrag(M2S, ab + ((ks * 64 + g * 16) ^ sw));
      f32x4 acc0 = {0.f, 0.f, 0.f, 0.f}, acc1 = {0.f, 0.f, 0.f, 0.f};
#pragma unroll
      for (int ks = 0; ks < 4; ks++) {
        acc0 = MFMA16(a[ks], w3f0[ks], acc0);
        acc1 = MFMA16(a[ks], w3f1[ks], acc1);
      }
      int cA = w * 32 + row, cB = w * 32 + 16 + row;
      float bbA = b3s[cA], bbB = b3s[cB];
      float s0 = 0.f, q0 = 0.f, s1 = 0.f, q1 = 0.f;
#pragma unroll
      for (int j = 0; j < 4; j++) {
        float hA = fmaxf(acc0[j] + bbA, 0.f);
        float hB = fmaxf(acc1[j] + bbB, 0.f);
        s0 += hA; q0 += hA * hA;
        s1 += hB; q1 += hB * hB;
      }
      s0 += __shfl_xor(s0, 16); s0 += __shfl_xor(s0, 32);
      q0 += __shfl_xor(q0, 16); q0 += __shfl_xor(q0, 32);
      s1 += __shfl_xor(s1, 16); s1 += __shfl_xor(s1, 32);
      q1 += __shfl_xor(q1, 16); q1 += __shfl_xor(q1, 32);
      if (g == 0) {
        size_t o = (size_t)tile * 4352 + v * 256;
        Ps3[o + cA] = s0; Pq3[o + cA] = q0;
        Ps3[o + cB] = s1; Pq3[o + cB] = q1;
      }
    }
  }
}

// head1: grid 32b x 8part, 256 thr. Partial sc3-weighted slice sums.
__global__ __launch_bounds__(256) void head1(const float* __restrict__ Ps3, const float* __restrict__ sc3,
                                             float* __restrict__ pp) {
  const int b = blockIdx.x >> 3, part = blockIdx.x & 7;
  const int tid = threadIdx.x;
  float a = 0.f;
#pragma unroll
  for (int v = 0; v < 17; v++) {
    float sbv = 0.f;
#pragma unroll
    for (int s2 = 0; s2 < 4; s2++)
      sbv += Ps3[(size_t)(b * 32 + part * 4 + s2) * 4352 + v * 256 + tid];
    a += sc3[v * 256 + tid] * sbv;
  }
  pp[(size_t)blockIdx.x * 256 + tid] = a;
}

// head2: grid 32, 256 thr. Sum partials + sh3 term, then 256x60 GEMM.
__global__ __launch_bounds__(256) void head2(const float* __restrict__ pp, const float* __restrict__ sh3,
                                             const float* __restrict__ Wf, const float* __restrict__ bf_,
                                             float* __restrict__ out) {
  __shared__ float pl[C3];
  const int b = blockIdx.x, tid = threadIdx.x;
  float a = 0.f;
#pragma unroll
  for (int p = 0; p < 8; p++) a += pp[(size_t)(b * 8 + p) * 256 + tid];
  float shs = 0.f;
#pragma unroll
  for (int v = 0; v < 17; v++) shs += sh3[v * 256 + tid];
  pl[tid] = a * (1.f / 8704.f) + shs * (1.f / 17.f);
  __syncthreads();
  if (tid < NCLS) {
    float acc = bf_[tid];
#pragma unroll 4
    for (int cc = 0; cc < C3; cc++) acc += pl[cc] * Wf[cc * NCLS + tid];
    out[b * NCLS + tid] = acc;
  }
}

// pass2h (tier-3): streams h1, saves m1A tiles to M1.
__global__ __launch_bounds__(512) void pass2h(const float* __restrict__ H1, const float* __restrict__ Nw,
                                              const float* __restrict__ sc1, const float* __restrict__ sh1,
                                              const short* __restrict__ W2p, const float* __restrict__ b2,
                                              float* __restrict__ Ps2, float* __restrict__ Pq2,
                                              float* __restrict__ M1) {
  __shared__ __align__(16) short m1A[17408];
  __shared__ float stats[4352];
  __shared__ float Ns[340];
  __shared__ float b2s[128];
  __shared__ float sc1s[1088], sh1s[1088];
  const int tid = threadIdx.x;
  const int lane = tid & 63, w = tid >> 6;
  const int row = lane & 15, g = lane >> 4;
  for (int i = tid; i < 340; i += 512) Ns[i] = Nw[i];
  if (tid < 128) b2s[tid] = b2[tid];
  for (int i = tid; i < 1088; i += 512) { sc1s[i] = sc1[i]; sh1s[i] = sh1[i]; }
  for (int i = tid; i < 4352; i += 512) stats[i] = 0.f;
  bf16x8 w2f0 = *reinterpret_cast<const bf16x8*>(&W2p[((w * 2 + 0) * 64 + lane) * 8]);
  bf16x8 w2f1 = *reinterpret_cast<const bf16x8*>(&W2p[((w * 2 + 1) * 64 + lane) * 8]);
  const int r_mix = tid >> 5;
  const int c2 = tid & 31;
  const int c = c2 * 2;
  __syncthreads();
  for (int chunk = 0; chunk < 2; chunk++) {
    const int rbase = blockIdx.x * 32 + chunk * 16;
    {
      const float* hrow = H1 + (size_t)(rbase + r_mix) * 1088;
      float t0[17], t1[17];
#pragma unroll
      for (int v = 0; v < 17; v++) {
        float2 hv = *reinterpret_cast<const float2*>(&hrow[v * 64 + c]);
        float2 scv = *reinterpret_cast<const float2*>(&sc1s[v * 64 + c]);
        float2 shv = *reinterpret_cast<const float2*>(&sh1s[v * 64 + c]);
        t0[v] = hv.x * scv.x + shv.x;
        t1[v] = hv.y * scv.y + shv.y;
      }
#pragma unroll
      for (int v = 0; v < 17; v++) {
        float a0 = 0.f, a1 = 0.f;
#pragma unroll
        for (int u0 = 0; u0 < 16; u0 += 4) {
          float4 n4 = *reinterpret_cast<const float4*>(&Ns[v * 20 + u0]);
          a0 += n4.x * t0[u0] + n4.y * t0[u0 + 1] + n4.z * t0[u0 + 2] + n4.w * t0[u0 + 3];
          a1 += n4.x * t1[u0] + n4.y * t1[u0 + 1] + n4.z * t1[u0 + 2] + n4.w * t1[u0 + 3];
        }
        float n16 = Ns[v * 20 + 16];
        a0 += n16 * t0[16]; a1 += n16 * t1[16];
        unsigned int pk = (f2bf(a1) << 16) | f2bf(a0);
        int off = v * 2048 + r_mix * 128 + ((c2 * 4) ^ ((r_mix & 7) << 4));
        *reinterpret_cast<unsigned int*>(reinterpret_cast<char*>(m1A) + off) = pk;
      }
    }
    __syncthreads();
#pragma unroll 1
    for (int v = 0; v < 17; v++) {
      int ab = v * 2048 + row * 128;
      int sw = (row & 7) << 4;
      bf16x8 a0 = afrag(m1A, ab + ((g * 16) ^ sw));
      bf16x8 a1 = afrag(m1A, ab + ((64 + g * 16) ^ sw));
      f32x4 acc = {0.f, 0.f, 0.f, 0.f};
      acc = MFMA16(a0, w2f0, acc);
      acc = MFMA16(a1, w2f1, acc);
      int cc = w * 16 + row;
      float bb = b2s[cc];
      float s = 0.f, q = 0.f;
#pragma unroll
      for (int j = 0; j < 4; j++) {
        float h = fmaxf(acc[j] + bb, 0.f);
        s += h; q += h * h;
      }
      s += __shfl_xor(s, 16); s += __shfl_xor(s, 32);
      q += __shfl_xor(q, 16); q += __shfl_xor(q, 32);
      if (g == 0) {
        stats[v * 128 + cc] += s;
        stats[2176 + v * 128 + cc] += q;
      }
    }
    {
      const int tile = blockIdx.x * 2 + chunk;
      float4* dst = reinterpret_cast<float4*>(M1 + (size_t)tile * 8704);
      const float4* src = reinterpret_cast<const float4*>(m1A);
      for (int i = tid; i < 2176; i += 512) dst[i] = src[i];
    }
    __syncthreads();
  }
  for (int i = tid; i < 2176; i += 512) {
    Ps2[(size_t)blockIdx.x * 2176 + i] = stats[i];
    Pq2[(size_t)blockIdx.x * 2176 + i] = stats[2176 + i];
  }
}

// pass3r (tier-3): register-resident pipeline over nchunk 16-row tiles.
__global__ __launch_bounds__(512) void pass3r(const float* __restrict__ M1, const float* __restrict__ Nw,
                                              const short* __restrict__ W2p, const float* __restrict__ b2,
                                              const float* __restrict__ sc2, const float* __restrict__ sh2,
                                              const short* __restrict__ W3p, const float* __restrict__ b3,
                                              float* __restrict__ Ps3, float* __restrict__ Pq3,
                                              int nchunk) {
  __shared__ __align__(16) char BUFA[34816];
  __shared__ __align__(16) short M2S[34816];
  __shared__ float Ns[340];
  __shared__ float b2s[128], b3s[256];
  __shared__ float sc2s[2176], sh2s[2176];
  const int tid = threadIdx.x;
  const int lane = tid & 63, w = tid >> 6;
  const int row = lane & 15, g = lane >> 4;
  const int cc = w * 16 + row;
  for (int i = tid; i < 340; i += 512) Ns[i] = Nw[i];
  if (tid < 128) b2s[tid] = b2[tid];
  if (tid < 256) b3s[tid] = b3[tid];
  for (int i = tid; i < 2176; i += 512) { sc2s[i] = sc2[i]; sh2s[i] = sh2[i]; }
  bf16x8 w2f0 = *reinterpret_cast<const bf16x8*>(&W2p[((w * 2 + 0) * 64 + lane) * 8]);
  bf16x8 w2f1 = *reinterpret_cast<const bf16x8*>(&W2p[((w * 2 + 1) * 64 + lane) * 8]);
  short* m1A = reinterpret_cast<short*>(BUFA);
  float* st  = reinterpret_cast<float*>(BUFA);
  __syncthreads();
  const float bb2 = b2s[cc];
  const int sw = (row & 7) << 4;
  for (int chunk = 0; chunk < nchunk; chunk++) {
    {
      const int tile = blockIdx.x * nchunk + chunk;
      const float4* src = reinterpret_cast<const float4*>(M1 + (size_t)tile * 8704);
      float4* dst = reinterpret_cast<float4*>(m1A);
      for (int i = tid; i < 2176; i += 512) dst[i] = src[i];
    }
    __syncthreads();
    float h[17][4];
#pragma unroll
    for (int v = 0; v < 17; v++) {
      int ab = v * 2048 + row * 128;
      bf16x8 a0 = afrag(m1A, ab + ((g * 16) ^ sw));
      bf16x8 a1 = afrag(m1A, ab + ((64 + g * 16) ^ sw));
      f32x4 acc = {0.f, 0.f, 0.f, 0.f};
      acc = MFMA16(a0, w2f0, acc);
      acc = MFMA16(a1, w2f1, acc);
      float scv = sc2s[v * 128 + cc], shv = sh2s[v * 128 + cc];
#pragma unroll
      for (int j = 0; j < 4; j++) h[v][j] = fmaxf(acc[j] + bb2, 0.f) * scv + shv;
      __builtin_amdgcn_sched_barrier(0);
    }
    __syncthreads();
    for (int i = tid; i < 8704; i += 512) st[i] = 0.f;
#pragma unroll
    for (int j = 0; j < 4; j++) {
      const int r = 4 * g + j;
      const int swr = (r & 7) << 4;
#pragma unroll
      for (int v = 0; v < 17; v++) {
        float a = 0.f;
#pragma unroll
        for (int u0 = 0; u0 < 16; u0 += 4) {
          float4 n4 = *reinterpret_cast<const float4*>(&Ns[v * 20 + u0]);
          a += n4.x * h[u0][j] + n4.y * h[u0 + 1][j] + n4.z * h[u0 + 2][j] + n4.w * h[u0 + 3][j];
        }
        a += Ns[v * 20 + 16] * h[16][j];
        int off = v * 4096 + r * 256 + ((cc * 2) ^ swr);
        *reinterpret_cast<short*>(reinterpret_cast<char*>(M2S) + off) = (short)f2bf(a);
      }
    }
    __syncthreads();
    {
      int z3 = 0;
      asm volatile("" : "+v"(z3));
      bf16x8 w3f0[4], w3f1[4];
#pragma unroll
      for (int ks = 0; ks < 4; ks++) {
        w3f0[ks] = *reinterpret_cast<const bf16x8*>(&W3p[(((w * 2 + 0) * 4 + ks) * 64 + lane) * 8 + z3]);
        w3f1[ks] = *reinterpret_cast<const bf16x8*>(&W3p[(((w * 2 + 1) * 4 + ks) * 64 + lane) * 8 + z3]);
      }
#pragma unroll 1
      for (int v = 0; v < 17; v++) {
        int ab = v * 4096 + row * 256;
        bf16x8 a[4];
#pragma unroll
        for (int ks = 0; ks < 4; ks++) a[ks] = afrag(M2S, ab + ((ks * 64 + g * 16) ^ sw));
        f32x4 acc0 = {0.f, 0.f, 0.f, 0.f}, acc1 = {0.f, 0.f, 0.f, 0.f};
#pragma unroll
        for (int ks = 0; ks < 4; ks++) {
          acc0 = MFMA16(a[ks], w3f0[ks], acc0);
          acc1 = MFMA16(a[ks], w3f1[ks], acc1);
        }
        int cA = w * 32 + row, cB = w * 32 + 16 + row;
        float bbA = b3s[cA], bbB = b3s[cB];
        float s0 = 0.f, q0 = 0.f, s1 = 0.f, q1 = 0.f;
#pragma unroll
        for (int j = 0; j < 4; j++) {
          float hA = fmaxf(acc0[j] + bbA, 0.f);
          float hB = fmaxf(acc1[j] + bbB, 0.f);
          s0 += hA; q0 += hA * hA;
          s1 += hB; q1 += hB * hB;
        }
        s0 += __shfl_xor(s0, 16); s0 += __shfl_xor(s0, 32);
        q0 += __shfl_xor(q0, 16); q0 += __shfl_xor(q0, 32);
        s1 += __shfl_xor(s1, 16); s1 += __shfl_xor(s1, 32);
        q1 += __shfl_xor(q1, 16); q1 += __shfl_xor(q1, 32);
        if (g == 0) {
          st[v * 256 + cA] += s0; st[4352 + v * 256 + cA] += q0;
          st[v * 256 + cB] += s1; st[4352 + v * 256 + cB] += q1;
        }
      }
    }
    __syncthreads();
    for (int i = tid; i < 4352; i += 512) {
      size_t o = (size_t)blockIdx.x * 4352 + i;
      if (chunk == 0) { Ps3[o] = st[i]; Pq3[o] = st[4352 + i]; }
      else            { Ps3[o] += st[i]; Pq3[o] += st[4352 + i]; }
    }
    __syncthreads();
  }
}

// headk (tier-3): original fused head.
__global__ __launch_bounds__(256) void headk(const float* __restrict__ Ps3, const float* __restrict__ sc3,
                                             const float* __restrict__ sh3, const float* __restrict__ Wf,
                                             const float* __restrict__ bf_, float* __restrict__ out, int NS) {
  __shared__ float pl[C3];
  int b = blockIdx.x, tid = threadIdx.x;
  float a = 0.f, shs = 0.f;
#pragma unroll
  for (int v = 0; v < 17; v++) {
    float sbv = 0.f;
    for (int s2 = 0; s2 < NS; s2++) sbv += Ps3[(size_t)(b * NS + s2) * 4352 + v * 256 + tid];
    a += sc3[v * 256 + tid] * sbv;
    shs += sh3[v * 256 + tid];
  }
  pl[tid] = a * (1.f / 8704.f) + shs * (1.f / 17.f);
  __syncthreads();
  if (tid < NCLS) {
    float acc = bf_[tid];
#pragma unroll 4
    for (int cc = 0; cc < C3; cc++) acc += pl[cc] * Wf[cc * NCLS + tid];
    out[b * NCLS + tid] = acc;
  }
}

// ==================== fallback path (round-1 kernels, used if ws too small) ====================
enum : int {
  FO_N = 0, FO_SC1 = 289, FO_SH1 = FO_SC1 + NV * C1, FO_SC2 = FO_SH1 + NV * C1,
  FO_SH2 = FO_SC2 + NV * C2, FO_SC3 = FO_SH2 + NV * C2, FO_SH3 = FO_SC3 + NV * C3,
  FO_ACC = FO_SH3 + NV * C3, FO_SUM1 = FO_ACC, FO_SQ1 = FO_SUM1 + NV * C1,
  FO_SUM2 = FO_SQ1 + NV * C1, FO_SQ2 = FO_SUM2 + NV * C2, FO_SUM3 = FO_SQ2 + NV * C2,
  FO_SQ3 = FO_SUM3 + NV * C3, FO_S = FO_SQ3 + NV * C3, FO_END = FO_S + BB * NV * C3,
};

__global__ __launch_bounds__(64) void build_NF(const int* __restrict__ ei, float* __restrict__ Nout) {
  __shared__ float A[NV][NV];
  __shared__ float dinv[NV];
  int tid = threadIdx.x;
  for (int i = tid; i < NV * NV; i += 64) A[i / NV][i % NV] = 0.f;
  __syncthreads();
  if (tid == 0) {
    for (int e = 0; e < 36; e++) { int s = ei[e], d = ei[36 + e]; A[d][s] += 1.f; }
    for (int v = 0; v < NV; v++) A[v][v] += 1.f;
  }
  __syncthreads();
  if (tid < NV) {
    float s = 0.f;
    for (int u = 0; u < NV; u++) s += A[tid][u];
    dinv[tid] = rsqrtf(s);
  }
  __syncthreads();
  for (int i = tid; i < NV * NV; i += 64) Nout[i] = dinv[i / NV] * A[i / NV][i % NV] * dinv[i % NV];
}

__global__ __launch_bounds__(256) void pass1F(const float* __restrict__ x, const float* __restrict__ Nm,
                                              const float* __restrict__ W1, const float* __restrict__ b1,
                                              float* __restrict__ sum1, float* __restrict__ sq1) {
  __shared__ float Ns[NV * NV];
  __shared__ float xr[4][51];
  int tid = threadIdx.x;
  int c = tid & 63, ty = tid >> 6;
  for (int i = tid; i < NV * NV; i += 256) Ns[i] = Nm[i];
  float w0 = W1[c], w1 = W1[64 + c], w2 = W1[128 + c], bb = b1[c];
  float sacc[NV], qacc[NV];
#pragma unroll
  for (int v = 0; v < NV; v++) { sacc[v] = 0.f; qacc[v] = 0.f; }
  __syncthreads();
  int base = blockIdx.x * 32;
  for (int i = 0; i < 8; i++) {
    int r = base + ty + 4 * i;
    __syncthreads();
    for (int j = c; j < 51; j += 64) xr[ty][j] = x[r * 51 + j];
    __syncthreads();
    float y1r[NV];
#pragma unroll
    for (int u = 0; u < NV; u++)
      y1r[u] = xr[ty][u * 3] * w0 + xr[ty][u * 3 + 1] * w1 + xr[ty][u * 3 + 2] * w2;
#pragma unroll
    for (int v = 0; v < NV; v++) {
      float h = bb;
#pragma unroll
      for (int u = 0; u < NV; u++) h += Ns[v * NV + u] * y1r[u];
      h = fmaxf(h, 0.f);
      sacc[v] += h; qacc[v] += h * h;
    }
  }
#pragma unroll
  for (int v = 0; v < NV; v++) {
    atomicAdd(&sum1[v * 64 + c], sacc[v]);
    atomicAdd(&sq1[v * 64 + c], qacc[v]);
  }
}

__global__ __launch_bounds__(256) void finalize_bnF(const float* __restrict__ sum, const float* __restrict__ sq,
                                                    const float* __restrict__ g, const float* __restrict__ be,
                                                    float* __restrict__ sc, float* __restrict__ sh, int n) {
  int i = blockIdx.x * 256 + threadIdx.x;
  if (i < n) {
    float m = sum[i] * (1.f / 16384.f);
    float v = sq[i] * (1.f / 16384.f) - m * m;
    float r = rsqrtf(v + 1e-5f);
    float s = g[i] * r;
    sc[i] = s;
    sh[i] = be[i] - m * s;
  }
}

__global__ __launch_bounds__(128) void pass2F(const float* __restrict__ x, const float* __restrict__ Nm,
                                              const float* __restrict__ W1, const float* __restrict__ b1,
                                              const float* __restrict__ sc1, const float* __restrict__ sh1,
                                              const float* __restrict__ W2, const float* __restrict__ b2,
                                              float* __restrict__ sum2, float* __restrict__ sq2) {
  __shared__ float Ns[NV * NV];
  __shared__ float xr[51];
  __shared__ __align__(16) float y1[NV * C1];
  __shared__ __align__(16) float h1n[NV * C1];
  int tid = threadIdx.x;
  for (int i = tid; i < NV * NV; i += 128) Ns[i] = Nm[i];
  float bb = b2[tid];
  float sacc[NV], qacc[NV];
#pragma unroll
  for (int v = 0; v < NV; v++) { sacc[v] = 0.f; qacc[v] = 0.f; }
  __syncthreads();
  int base = blockIdx.x * 16;
  for (int i = 0; i < 16; i++) {
    int r = base + i;
    __syncthreads();
    if (tid < 51) xr[tid] = x[r * 51 + tid];
    __syncthreads();
    for (int idx = tid; idx < NV * C1; idx += 128) {
      int u = idx >> 6, cc = idx & 63;
      y1[idx] = xr[u * 3] * W1[cc] + xr[u * 3 + 1] * W1[64 + cc] + xr[u * 3 + 2] * W1[128 + cc];
    }
    __syncthreads();
    for (int idx = tid; idx < NV * C1; idx += 128) {
      int v = idx >> 6, cc = idx & 63;
      float h = b1[cc];
#pragma unroll
      for (int u = 0; u < NV; u++) h += Ns[v * NV + u] * y1[u * 64 + cc];
      h1n[idx] = fmaxf(h, 0.f) * sc1[idx] + sh1[idx];
    }
    __syncthreads();
    float y2r[NV];
#pragma unroll
    for (int u = 0; u < NV; u++) y2r[u] = 0.f;
#pragma unroll 2
    for (int k0 = 0; k0 < 64; k0 += 4) {
      float wa = W2[(k0)*128 + tid];
      float wb = W2[(k0 + 1) * 128 + tid];
      float wc = W2[(k0 + 2) * 128 + tid];
      float wd = W2[(k0 + 3) * 128 + tid];
#pragma unroll
      for (int u = 0; u < NV; u++) {
        float4 h4 = *reinterpret_cast<const float4*>(&h1n[u * 64 + k0]);
        y2r[u] += h4.x * wa + h4.y * wb + h4.z * wc + h4.w * wd;
      }
    }
#pragma unroll
    for (int v = 0; v < NV; v++) {
      float h = bb;
#pragma unroll
      for (int u = 0; u < NV; u++) h += Ns[v * NV + u] * y2r[u];
      h = fmaxf(h, 0.f);
      sacc[v] += h; qacc[v] += h * h;
    }
  }
#pragma unroll
  for (int v = 0; v < NV; v++) {
    atomicAdd(&sum2[v * 128 + tid], sacc[v]);
    atomicAdd(&sq2[v * 128 + tid], qacc[v]);
  }
}

__global__ __launch_bounds__(128) void pass3F(const float* __restrict__ x, const float* __restrict__ Nm,
                                              const float* __restrict__ W1, const float* __restrict__ b1,
                                              const float* __restrict__ sc1, const float* __restrict__ sh1,
                                              const float* __restrict__ W2, const float* __restrict__ b2,
                                              const float* __restrict__ sc2, const float* __restrict__ sh2,
                                              const float* __restrict__ W3, const float* __restrict__ b3,
                                              float* __restrict__ sum3, float* __restrict__ sq3,
                                              float* __restrict__ S) {
  __shared__ float Ns[NV * NV];
  __shared__ float xr[51];
  __shared__ __align__(16) float y1[NV * C1];
  __shared__ __align__(16) float h1n[NV * C1];
  __shared__ __align__(16) float h2n[NV * C2];
  int tid = threadIdx.x;
  int b = blockIdx.x >> 5, chunk = blockIdx.x & 31;
  int rbase = b * TT + chunk * 16;
  for (int i = tid; i < NV * NV; i += 128) Ns[i] = Nm[i];
  float bb2 = b2[tid];
  float b3a = b3[tid], b3b = b3[tid + 128];
  float sA[NV], qA[NV], sB[NV], qB[NV];
#pragma unroll
  for (int v = 0; v < NV; v++) { sA[v] = 0.f; qA[v] = 0.f; sB[v] = 0.f; qB[v] = 0.f; }
  __syncthreads();
  for (int i = 0; i < 16; i++) {
    int r = rbase + i;
    __syncthreads();
    if (tid < 51) xr[tid] = x[r * 51 + tid];
    __syncthreads();
    for (int idx = tid; idx < NV * C1; idx += 128) {
      int u = idx >> 6, cc = idx & 63;
      y1[idx] = xr[u * 3] * W1[cc] + xr[u * 3 + 1] * W1[64 + cc] + xr[u * 3 + 2] * W1[128 + cc];
    }
    __syncthreads();
    for (int idx = tid; idx < NV * C1; idx += 128) {
      int v = idx >> 6, cc = idx & 63;
      float h = b1[cc];
#pragma unroll
      for (int u = 0; u < NV; u++) h += Ns[v * NV + u] * y1[u * 64 + cc];
      h1n[idx] = fmaxf(h, 0.f) * sc1[idx] + sh1[idx];
    }
    __syncthreads();
    {
      float y2r[NV];
#pragma unroll
      for (int u = 0; u < NV; u++) y2r[u] = 0.f;
#pragma unroll 2
      for (int k0 = 0; k0 < 64; k0 += 4) {
        float wa = W2[(k0)*128 + tid];
        float wb = W2[(k0 + 1) * 128 + tid];
        float wc = W2[(k0 + 2) * 128 + tid];
        float wd = W2[(k0 + 3) * 128 + tid];
#pragma unroll
        for (int u = 0; u < NV; u++) {
          float4 h4 = *reinterpret_cast<const float4*>(&h1n[u * 64 + k0]);
          y2r[u] += h4.x * wa + h4.y * wb + h4.z * wc + h4.w * wd;
        }
      }
#pragma unroll
      for (int v = 0; v < NV; v++) {
        float h = bb2;
#pragma unroll
        for (int u = 0; u < NV; u++) h += Ns[v * NV + u] * y2r[u];
        int e = v * 128 + tid;
        h2n[e] = fmaxf(h, 0.f) * sc2[e] + sh2[e];
      }
    }
    __syncthreads();
    float y3a[NV], y3b[NV];
#pragma unroll
    for (int u = 0; u < NV; u++) { y3a[u] = 0.f; y3b[u] = 0.f; }
#pragma unroll 2
    for (int k0 = 0; k0 < 128; k0 += 4) {
      float wa0 = W3[(k0)*256 + tid], wb0 = W3[(k0)*256 + 128 + tid];
      float wa1 = W3[(k0 + 1) * 256 + tid], wb1 = W3[(k0 + 1) * 256 + 128 + tid];
      float wa2 = W3[(k0 + 2) * 256 + tid], wb2 = W3[(k0 + 2) * 256 + 128 + tid];
      float wa3 = W3[(k0 + 3) * 256 + tid], wb3 = W3[(k0 + 3) * 256 + 128 + tid];
#pragma unroll
      for (int u = 0; u < NV; u++) {
        float4 h4 = *reinterpret_cast<const float4*>(&h2n[u * 128 + k0]);
        y3a[u] += h4.x * wa0 + h4.y * wa1 + h4.z * wa2 + h4.w * wa3;
        y3b[u] += h4.x * wb0 + h4.y * wb1 + h4.z * wb2 + h4.w * wb3;
      }
    }
#pragma unroll
    for (int v = 0; v < NV; v++) {
      float ha = b3a, hb = b3b;
#pragma unroll
      for (int u = 0; u < NV; u++) {
        float nn = Ns[v * NV + u];
        ha += nn * y3a[u];
        hb += nn * y3b[u];
      }
      ha = fmaxf(ha, 0.f); hb = fmaxf(hb, 0.f);
      sA[v] += ha; qA[v] += ha * ha;
      sB[v] += hb; qB[v] += hb * hb;
    }
  }
#pragma unroll
  for (int v = 0; v < NV; v++) {
    int ea = v * 256 + tid, eb = ea + 128;
    atomicAdd(&sum3[ea], sA[v]); atomicAdd(&sq3[ea], qA[v]);
    atomicAdd(&sum3[eb], sB[v]); atomicAdd(&sq3[eb], qB[v]);
    atomicAdd(&S[b * (NV * C3) + ea], sA[v]);
    atomicAdd(&S[b * (NV * C3) + eb], sB[v]);
  }
}

__global__ __launch_bounds__(256) void headF(const float* __restrict__ S, const float* __restrict__ sc3,
                                             const float* __restrict__ sh3, const float* __restrict__ Wf,
                                             const float* __restrict__ bf, float* __restrict__ out) {
  __shared__ float pl[C3];
  int b = blockIdx.x, tid = threadIdx.x;
  float a = 0.f, sh = 0.f;
#pragma unroll
  for (int v = 0; v < NV; v++) {
    int e = v * 256 + tid;
    a += S[b * (NV * C3) + e] * sc3[e];
    sh += sh3[e];
  }
  pl[tid] = a * (1.f / 8704.f) + sh * (1.f / 17.f);
  __syncthreads();
  if (tid < NCLS) {
    float acc = bf[tid];
#pragma unroll 4
    for (int c = 0; c < C3; c++) acc += pl[c] * Wf[c * NCLS + tid];
    out[b * NCLS + tid] = acc;
  }
}

extern "C" void kernel_launch(void* const* d_in, const int* in_sizes, int n_in,
                              void* d_out, int out_size, void* d_ws, size_t ws_size,
                              hipStream_t stream) {
  (void)in_sizes; (void)n_in; (void)out_size;
  const float* x   = (const float*)d_in[0];
  const int*   ei  = (const int*)d_in[1];
  const float* W1  = (const float*)d_in[2];
  const float* b1  = (const float*)d_in[3];
  const float* g1  = (const float*)d_in[4];
  const float* be1 = (const float*)d_in[5];
  const float* W2  = (const float*)d_in[6];
  const float* b2  = (const float*)d_in[7];
  const float* g2  = (const float*)d_in[8];
  const float* be2 = (const float*)d_in[9];
  const float* W3  = (const float*)d_in[10];
  const float* b3  = (const float*)d_in[11];
  const float* g3  = (const float*)d_in[12];
  const float* be3 = (const float*)d_in[13];
  const float* Wf  = (const float*)d_in[14];
  const float* bf  = (const float*)d_in[15];
  float* ws = (float*)d_ws;

  if (ws_size >= (size_t)T4_END * sizeof(float)) {
    // -------- tier-4 (R9 config, best verified): split head, wide finalize --------
    build_Npad<<<1, 64, 0, stream>>>(ei, ws + T4_N);
    repackk<<<160, 256, 0, stream>>>(W2, W3, (short*)(ws + T4_W2P), (short*)(ws + T4_W3P));
    pass1w<<<512, 512, 0, stream>>>(x, ws + T4_N, W1, b1, ws + T4_H1);
    stats1k<<<512, 512, 0, stream>>>(ws + T4_H1, ws + T4_PS1, ws + T4_PQ1);
    finalize_k<<<17, 1024, 0, stream>>>(ws + T4_PS1, ws + T4_PQ1, 512, 1088, g1, be1, ws + T4_SC1, ws + T4_SH1);
    pass2g<<<1024, 512, 0, stream>>>(ws + T4_H1, ws + T4_N, ws + T4_SC1, ws + T4_SH1,
                                     (const short*)(ws + T4_W2P), b2, ws + T4_PS3, ws + T4_PQ3,
                                     (short*)(ws + T4_H2));
    finalize_k<<<34, 1024, 0, stream>>>(ws + T4_PS3, ws + T4_PQ3, 1024, 2176, g2, be2, ws + T4_SC2, ws + T4_SH2);
    pass3h<<<1024, 512, 0, stream>>>((const short*)(ws + T4_H2), ws + T4_N,
                                     ws + T4_SC2, ws + T4_SH2,
                                     (const short*)(ws + T4_W3P), b3, ws + T4_PS3, ws + T4_PQ3);
    finalize_k<<<68, 1024, 0, stream>>>(ws + T4_PS3, ws + T4_PQ3, 1024, 4352, g3, be3, ws + T4_SC3, ws + T4_SH3);
    head1<<<256, 256, 0, stream>>>(ws + T4_PS3, ws + T4_SC3, ws + T4_PP);
    head2<<<BB, 256, 0, stream>>>(ws + T4_PP, ws + T4_SH3, Wf, bf, (float*)d_out);
  } else if (ws_size >= (size_t)T3_END * sizeof(float)) {
    // -------- tier-3: H1-dedup path --------
    build_Npad<<<1, 64, 0, stream>>>(ei, ws + T3_N);
    repackk<<<160, 256, 0, stream>>>(W2, W3, (short*)(ws + T3_W2P), (short*)(ws + T3_W3P));
    pass1k<<<512, 512, 0, stream>>>(x, ws + T3_N, W1, b1, ws + T3_PS1, ws + T3_PQ1, ws + T3_H1);
    finalize_k<<<17, 1024, 0, stream>>>(ws + T3_PS1, ws + T3_PQ1, 512, 1088, g1, be1, ws + T3_SC1, ws + T3_SH1);
    pass2h<<<512, 512, 0, stream>>>(ws + T3_H1, ws + T3_N, ws + T3_SC1, ws + T3_SH1,
                                    (const short*)(ws + T3_W2P), b2, ws + T3_PS2, ws + T3_PQ2, ws + T3_M1);
    finalize_k<<<34, 1024, 0, stream>>>(ws + T3_PS2, ws + T3_PQ2, 512, 2176, g2, be2, ws + T3_SC2, ws + T3_SH2);
    pass3r<<<1024, 512, 0, stream>>>(ws + T3_M1, ws + T3_N,
                                     (const short*)(ws + T3_W2P), b2, ws + T3_SC2, ws + T3_SH2,
                                     (const short*)(ws + T3_W3P), b3, ws + T3_PS3, ws + T3_PQ3, 1);
    finalize_k<<<68, 1024, 0, stream>>>(ws + T3_PS3, ws + T3_PQ3, 1024, 4352, g3, be3, ws + T3_SC3, ws + T3_SH3);
    headk<<<BB, 256, 0, stream>>>(ws + T3_PS3, ws + T3_SC3, ws + T3_SH3, Wf, bf, (float*)d_out, 32);
  } else {
    // -------- fallback (round-1 scalar path) --------
    float* Nm   = ws + FO_N;
    float* sc1  = ws + FO_SC1; float* sh1 = ws + FO_SH1;
    float* sc2  = ws + FO_SC2; float* sh2 = ws + FO_SH2;
    float* sc3  = ws + FO_SC3; float* sh3 = ws + FO_SH3;
    float* sum1 = ws + FO_SUM1; float* sq1 = ws + FO_SQ1;
    float* sum2 = ws + FO_SUM2; float* sq2 = ws + FO_SQ2;
    float* sum3 = ws + FO_SUM3; float* sq3 = ws + FO_SQ3;
    float* S    = ws + FO_S;

    hipMemsetAsync(ws + FO_ACC, 0, (size_t)(FO_END - FO_ACC) * sizeof(float), stream);
    build_NF<<<1, 64, 0, stream>>>(ei, Nm);
    pass1F<<<512, 256, 0, stream>>>(x, Nm, W1, b1, sum1, sq1);
    finalize_bnF<<<(NV * C1 + 255) / 256, 256, 0, stream>>>(sum1, sq1, g1, be1, sc1, sh1, NV * C1);
    pass2F<<<1024, 128, 0, stream>>>(x, Nm, W1, b1, sc1, sh1, W2, b2, sum2, sq2);
    finalize_bnF<<<(NV * C2 + 255) / 256, 256, 0, stream>>>(sum2, sq2, g2, be2, sc2, sh2, NV * C2);
    pass3F<<<1024, 128, 0, stream>>>(x, Nm, W1, b1, sc1, sh1, W2, b2, sc2, sh2, W3, b3, sum3, sq3, S);
    finalize_bnF<<<(NV * C3 + 255) / 256, 256, 0, stream>>>(sum3, sq3, g3, be3, sc3, sh3, NV * C3);
    headF<<<BB, 256, 0, stream>>>(S, sc3, sh3, Wf, bf, (float*)d_out);
  }
}